// Round 1
// baseline (9568.674 us; speedup 1.0000x reference)
//
#include <hip/hip_runtime.h>
#include <hip/hip_bf16.h>
#include <math.h>

#define NSEQ 2048
#define NDIM 768
#define NLAY 8
#define NHEAD 6
#define NHD 128
#define NVOC 50257
#define NBLK 16
#define BLKSZ 128
#define EOS_TOK 50256
#define EPSF 1.1920929e-07f
#define ASCALE 0.12f
#define VCHUNK 2048
#define NCHUNK 25

__device__ __forceinline__ float bf16r(float x) {
  return __bfloat162float(__float2bfloat16(x));
}

// ---------------- prep: docs cumsum + block mask categories ----------------
__global__ __launch_bounds__(1024) void prep_kernel(const int* __restrict__ seq, const int* __restrict__ wptr,
                                                    int* __restrict__ docs, int* __restrict__ catL,
                                                    int* __restrict__ catS) {
  __shared__ int f[NSEQ];
  __shared__ int g[NSEQ];
  int tid = threadIdx.x;
  for (int i = tid; i < NSEQ; i += 1024) f[i] = (seq[i] == EOS_TOK) ? 1 : 0;
  __syncthreads();
  int* a = f; int* b = g;
  for (int off = 1; off < NSEQ; off <<= 1) {
    for (int i = tid; i < NSEQ; i += 1024) {
      int v = a[i];
      if (i >= off) v += a[i - off];
      b[i] = v;
    }
    __syncthreads();
    int* t = a; a = b; b = t;
  }
  for (int i = tid; i < NSEQ; i += 1024) docs[i] = a[i];
  __syncthreads();
  if (tid == 0) {
    int dl[NBLK], dh[NBLK];
    for (int bi = 0; bi < NBLK; ++bi) { dl[bi] = a[bi * BLKSZ]; dh[bi] = a[bi * BLKSZ + BLKSZ - 1]; }
    int W = *wptr;
    for (int pass = 0; pass < 2; ++pass) {
      int w = (pass == 0) ? W : (W / 2);
      int* cat = (pass == 0) ? catL : catS;
      for (int i = 0; i < NBLK; ++i) {
        int allr[NBLK], partr[NBLK];
        int nf = 0, np = 0;
        for (int j = 0; j < NBLK; ++j) {
          int any_ = (i >= j) && (dl[i] <= dh[j]) && (dh[i] >= dl[j]);
          int all_ = (i > j) && (dl[i] == dh[j]) && (dh[i] == dl[j]);
          allr[j] = all_; partr[j] = any_ && !all_;
          nf += all_; np += partr[j];
        }
        int kcf = min(nf, w - 1);
        int kcp = min(np, max(w - nf, 1));
        int cf = 0, cp = 0;
        for (int j = NBLK - 1; j >= 0; --j) {
          int cv = 0;
          if (allr[j]) { cf++; if (cf <= kcf) cv = 2; }
          if (partr[j]) { cp++; if (cp <= kcp) cv = 1; }
          cat[i * NBLK + j] = cv;
        }
      }
    }
  }
}

// ---------------- embedding gather + rms -> x, x0 ----------------
__global__ __launch_bounds__(256) void embed_rms_kernel(const int* __restrict__ seq, const float* __restrict__ embed,
                                                        float* __restrict__ x, float* __restrict__ x0) {
  int s = blockIdx.x;
  int tid = threadIdx.x;
  const float* row = embed + (size_t)seq[s] * NDIM;
  float v0 = row[tid], v1 = row[tid + 256], v2 = row[tid + 512];
  float ss = v0 * v0 + v1 * v1 + v2 * v2;
  __shared__ float red[256];
  red[tid] = ss; __syncthreads();
  for (int o = 128; o > 0; o >>= 1) { if (tid < o) red[tid] += red[tid + o]; __syncthreads(); }
  float sc = rsqrtf(red[0] / (float)NDIM + EPSF);
  size_t base = (size_t)s * NDIM;
  float o0 = v0 * sc, o1 = v1 * sc, o2 = v2 * sc;
  x[base + tid] = o0; x[base + tid + 256] = o1; x[base + tid + 512] = o2;
  x0[base + tid] = o0; x0[base + tid + 256] = o1; x0[base + tid + 512] = o2;
}

// ---------------- row rms: xa = rms(x) ----------------
__global__ __launch_bounds__(256) void rms_kernel(const float* __restrict__ x, float* __restrict__ xa) {
  int s = blockIdx.x;
  int tid = threadIdx.x;
  size_t base = (size_t)s * NDIM;
  float v0 = x[base + tid], v1 = x[base + tid + 256], v2 = x[base + tid + 512];
  float ss = v0 * v0 + v1 * v1 + v2 * v2;
  __shared__ float red[256];
  red[tid] = ss; __syncthreads();
  for (int o = 128; o > 0; o >>= 1) { if (tid < o) red[tid] += red[tid + o]; __syncthreads(); }
  float sc = rsqrtf(red[0] / (float)NDIM + EPSF);
  xa[base + tid] = v0 * sc; xa[base + tid + 256] = v1 * sc; xa[base + tid + 512] = v2 * sc;
}

// ---------------- residual mix: x = lam0*(x + sw*skip) + lam1*x0 ----------------
__global__ __launch_bounds__(256) void mix_kernel(float* __restrict__ x, const float* __restrict__ x0,
                                                  const float* __restrict__ skip, const float* __restrict__ scal,
                                                  int li, int sj) {
  float lam0 = scal[NLAY + 2 * li], lam1 = scal[NLAY + 2 * li + 1];
  float sw = (sj >= 0) ? scal[sj] : 0.f;
  int n4 = NSEQ * NDIM / 4;
  float4* x4 = (float4*)x;
  const float4* o4 = (const float4*)x0;
  const float4* s4 = (const float4*)skip;
  for (int i = blockIdx.x * blockDim.x + threadIdx.x; i < n4; i += gridDim.x * blockDim.x) {
    float4 xv = x4[i];
    float4 ov = o4[i];
    if (skip) {
      float4 sv = s4[i];
      xv.x += sw * sv.x; xv.y += sw * sv.y; xv.z += sw * sv.z; xv.w += sw * sv.w;
    }
    xv.x = lam0 * xv.x + lam1 * ov.x; xv.y = lam0 * xv.y + lam1 * ov.y;
    xv.z = lam0 * xv.z + lam1 * ov.z; xv.w = lam0 * xv.w + lam1 * ov.w;
    x4[i] = xv;
  }
}

// ---------------- generic f32 GEMM: C[m][n] op= sum_k A[m][k]*B[n][k] ----------------
// MODE 0: store, 1: accumulate into C, 2: relu(acc)^2
template <int MODE>
__global__ __launch_bounds__(256) void gemm64(const float* __restrict__ A, const float* __restrict__ B,
                                              float* __restrict__ C, int N, int K) {
  __shared__ float As[64][17];
  __shared__ float Bs[16][64];
  int bm = blockIdx.x * 64, bn = blockIdx.y * 64;
  int tid = threadIdx.x;
  int tm = tid >> 4, tn = tid & 15;
  int lr = tid >> 2, lc = (tid & 3) << 2;
  const float* Ap = A + (size_t)(bm + lr) * K + lc;
  const float* Bp = B + (size_t)(bn + lr) * K + lc;
  float acc[4][4] = {};
  for (int k0 = 0; k0 < K; k0 += 16) {
    float4 av = *(const float4*)(Ap + k0);
    float4 bv = *(const float4*)(Bp + k0);
    As[lr][lc + 0] = av.x; As[lr][lc + 1] = av.y; As[lr][lc + 2] = av.z; As[lr][lc + 3] = av.w;
    Bs[lc + 0][lr] = bv.x; Bs[lc + 1][lr] = bv.y; Bs[lc + 2][lr] = bv.z; Bs[lc + 3][lr] = bv.w;
    __syncthreads();
#pragma unroll
    for (int k = 0; k < 16; ++k) {
      float a0 = As[tm * 4 + 0][k], a1 = As[tm * 4 + 1][k], a2 = As[tm * 4 + 2][k], a3 = As[tm * 4 + 3][k];
      float4 bq = *(const float4*)&Bs[k][tn * 4];
      acc[0][0] += a0 * bq.x; acc[0][1] += a0 * bq.y; acc[0][2] += a0 * bq.z; acc[0][3] += a0 * bq.w;
      acc[1][0] += a1 * bq.x; acc[1][1] += a1 * bq.y; acc[1][2] += a1 * bq.z; acc[1][3] += a1 * bq.w;
      acc[2][0] += a2 * bq.x; acc[2][1] += a2 * bq.y; acc[2][2] += a2 * bq.z; acc[2][3] += a2 * bq.w;
      acc[3][0] += a3 * bq.x; acc[3][1] += a3 * bq.y; acc[3][2] += a3 * bq.z; acc[3][3] += a3 * bq.w;
    }
    __syncthreads();
  }
#pragma unroll
  for (int i = 0; i < 4; ++i)
#pragma unroll
    for (int j = 0; j < 4; ++j) {
      size_t ci = (size_t)(bm + tm * 4 + i) * N + (bn + tn * 4 + j);
      if (MODE == 0) C[ci] = acc[i][j];
      else if (MODE == 1) C[ci] += acc[i][j];
      else { float r = fmaxf(acc[i][j], 0.f); C[ci] = r * r; }
    }
}

// ---------------- qkv post: per-head rms + rope for q,k; value mix for v ----------------
__global__ __launch_bounds__(128) void qkv_post_kernel(const float* __restrict__ qkv, const float* __restrict__ vemb,
                                                       const int* __restrict__ seq, const float* __restrict__ scal,
                                                       int li, int ve_idx,
                                                       float* __restrict__ qo, float* __restrict__ ko,
                                                       float* __restrict__ vo) {
  int s = blockIdx.x;
  int d = threadIdx.x;
  __shared__ float red[128];
  __shared__ float qn[128], kn[128];
  float sal0 = scal[3 * NLAY + 2 * li], sal1 = scal[3 * NLAY + 2 * li + 1];
  int j = d & 63;
  float fr = (j < 32) ? powf(1.0f / 1024.0f, (float)j * (1.0f / 31.0f)) : 0.f;
  float th = (float)s * fr;
  float cth = cosf(th), sth = sinf(th);
  int tok = seq[s];
  for (int h = 0; h < NHEAD; ++h) {
    size_t rb = (size_t)s * (3 * NHEAD * NHD);
    float qv = qkv[rb + h * NHD + d];
    float kv = qkv[rb + NHEAD * NHD + h * NHD + d];
    float vv = qkv[rb + 2 * NHEAD * NHD + h * NHD + d];
    red[d] = qv * qv; __syncthreads();
    for (int o = 64; o > 0; o >>= 1) { if (d < o) red[d] += red[d + o]; __syncthreads(); }
    float sq = red[0]; __syncthreads();
    red[d] = kv * kv; __syncthreads();
    for (int o = 64; o > 0; o >>= 1) { if (d < o) red[d] += red[d + o]; __syncthreads(); }
    float sk = red[0]; __syncthreads();
    qn[d] = qv * rsqrtf(sq / (float)NHD + EPSF);
    kn[d] = kv * rsqrtf(sk / (float)NHD + EPSF);
    __syncthreads();
    float oq, ok;
    if (d < 64) { oq = qn[d] * cth + qn[d + 64] * sth; ok = kn[d] * cth + kn[d + 64] * sth; }
    else        { oq = -qn[j] * sth + qn[j + 64] * cth; ok = -kn[j] * sth + kn[j + 64] * cth; }
    float ov = sal0 * vv;
    if (ve_idx >= 0) ov += sal1 * vemb[((size_t)ve_idx * NVOC + tok) * NDIM + h * NHD + d];
    size_t oo = ((size_t)h * NSEQ + s) * NHD + d;
    qo[oo] = oq; ko[oo] = ok; vo[oo] = ov;
    __syncthreads();
  }
}

// ---------------- flash attention with block-category masks ----------------
// grid (NSEQ/32, NHEAD), 128 threads; 4 lanes per q-row (32 dims each)
__global__ __launch_bounds__(128) void attn_kernel(const float* __restrict__ q, const float* __restrict__ k,
                                                   const float* __restrict__ v, const int* __restrict__ cat,
                                                   const int* __restrict__ docs, float* __restrict__ y) {
  int qb = blockIdx.x;
  int h = blockIdx.y;
  int tid = threadIdx.x;
  int r = tid >> 2;
  int qt = tid & 3;
  int rg = qb * 32 + r;
  int qB = qb >> 2;  // 128-block index of all rows in this workgroup
  __shared__ float Ks[32][NHD];
  __shared__ float Vs[32][NHD];
  __shared__ int kd[32];
  const float4* qp = (const float4*)(q + ((size_t)h * NSEQ + rg) * NHD + qt * 32);
  float4 qv[8];
#pragma unroll
  for (int i = 0; i < 8; ++i) qv[i] = qp[i];
  float acc[32];
#pragma unroll
  for (int i = 0; i < 32; ++i) acc[i] = 0.f;
  float mrun = -INFINITY, lrun = 0.f;
  int mydoc = docs[rg];
  int nkb = (qB + 1) * (BLKSZ / 32);
  for (int kb = 0; kb < nkb; ++kb) {
    int c = cat[qB * NBLK + (kb >> 2)];
    if (c == 0) continue;
    __syncthreads();
    {
      const float4* ksrc = (const float4*)(k + ((size_t)h * NSEQ + kb * 32) * NHD);
      const float4* vsrc = (const float4*)(v + ((size_t)h * NSEQ + kb * 32) * NHD);
      float4* kdst = (float4*)&Ks[0][0];
      float4* vdst = (float4*)&Vs[0][0];
      for (int i = tid; i < 32 * NHD / 4; i += 128) { kdst[i] = ksrc[i]; vdst[i] = vsrc[i]; }
      if (tid < 32) kd[tid] = docs[kb * 32 + tid];
    }
    __syncthreads();
    float sc[32];
#pragma unroll
    for (int kk = 0; kk < 32; ++kk) {
      const float4* kp = (const float4*)&Ks[kk][qt * 32];
      float sa = 0.f;
#pragma unroll
      for (int i = 0; i < 8; ++i) {
        float4 aa = qv[i], bb = kp[i];
        sa += aa.x * bb.x + aa.y * bb.y + aa.z * bb.z + aa.w * bb.w;
      }
      sa += __shfl_xor(sa, 1, 64);
      sa += __shfl_xor(sa, 2, 64);
      int kg = kb * 32 + kk;
      bool okm = (c == 2) || ((kg <= rg) && (kd[kk] == mydoc));
      sc[kk] = okm ? sa * ASCALE : -INFINITY;
    }
    float bmx = sc[0];
#pragma unroll
    for (int kk = 1; kk < 32; ++kk) bmx = fmaxf(bmx, sc[kk]);
    float mnew = fmaxf(mrun, bmx);
    if (mnew == -INFINITY) continue;  // nothing allowed yet for this row
    float corr = __expf(mrun - mnew);
    lrun *= corr;
#pragma unroll
    for (int i = 0; i < 32; ++i) acc[i] *= corr;
#pragma unroll
    for (int kk = 0; kk < 32; ++kk) {
      float p = __expf(sc[kk] - mnew);
      lrun += p;
      const float* vp = &Vs[kk][qt * 32];
#pragma unroll
      for (int i = 0; i < 32; ++i) acc[i] += p * vp[i];
    }
    mrun = mnew;
  }
  float inv = 1.f / lrun;
  float* yo = y + (size_t)rg * (NHEAD * NHD) + h * NHD + qt * 32;
#pragma unroll
  for (int i = 0; i < 32; ++i) yo[i] = acc[i] * inv;
}

// ---------------- fused logits + soft-cap + online logsumexp per vocab chunk ----------------
__global__ __launch_bounds__(256) void logits_lse_kernel(const float* __restrict__ xf, const float* __restrict__ embed,
                                                         const int* __restrict__ target,
                                                         float* __restrict__ part_m, float* __restrict__ part_l,
                                                         float* __restrict__ tcap) {
  int tb = blockIdx.x;
  int ch = blockIdx.y;
  int tid = threadIdx.x;
  int tm = tid >> 4, tn = tid & 15;
  int lr = tid >> 2, lc = (tid & 3) << 2;
  __shared__ float As[64][17];
  __shared__ float Bs[16][64];
  __shared__ float redm[64][17];
  __shared__ float rtm[64];
  __shared__ float rowm[64], rowl[64];
  if (tid < 64) { rowm[tid] = -INFINITY; rowl[tid] = 0.f; }
  int tg[4];
#pragma unroll
  for (int i = 0; i < 4; ++i) tg[i] = target[tb * 64 + tm * 4 + i];
  const float* Ap = xf + (size_t)(tb * 64 + lr) * NDIM + lc;
  __syncthreads();
  for (int vt = 0; vt < VCHUNK / 64; ++vt) {
    int vb = ch * VCHUNK + vt * 64;
    if (vb >= NVOC) break;
    float acc[4][4] = {};
    int brow = vb + lr;
    const float* Bp = embed + (size_t)brow * NDIM + lc;
    bool bok = brow < NVOC;
    for (int k0 = 0; k0 < NDIM; k0 += 16) {
      float4 av = *(const float4*)(Ap + k0);
      As[lr][lc + 0] = bf16r(av.x); As[lr][lc + 1] = bf16r(av.y);
      As[lr][lc + 2] = bf16r(av.z); As[lr][lc + 3] = bf16r(av.w);
      float4 bv = bok ? *(const float4*)(Bp + k0) : make_float4(0.f, 0.f, 0.f, 0.f);
      Bs[lc + 0][lr] = bf16r(bv.x); Bs[lc + 1][lr] = bf16r(bv.y);
      Bs[lc + 2][lr] = bf16r(bv.z); Bs[lc + 3][lr] = bf16r(bv.w);
      __syncthreads();
#pragma unroll
      for (int kk = 0; kk < 16; ++kk) {
        float a0 = As[tm * 4 + 0][kk], a1 = As[tm * 4 + 1][kk], a2 = As[tm * 4 + 2][kk], a3 = As[tm * 4 + 3][kk];
        float4 bq = *(const float4*)&Bs[kk][tn * 4];
        acc[0][0] += a0 * bq.x; acc[0][1] += a0 * bq.y; acc[0][2] += a0 * bq.z; acc[0][3] += a0 * bq.w;
        acc[1][0] += a1 * bq.x; acc[1][1] += a1 * bq.y; acc[1][2] += a1 * bq.z; acc[1][3] += a1 * bq.w;
        acc[2][0] += a2 * bq.x; acc[2][1] += a2 * bq.y; acc[2][2] += a2 * bq.z; acc[2][3] += a2 * bq.w;
        acc[3][0] += a3 * bq.x; acc[3][1] += a3 * bq.y; acc[3][2] += a3 * bq.z; acc[3][3] += a3 * bq.w;
      }
      __syncthreads();
    }
    float capv[4][4];
    float pmax[4];
#pragma unroll
    for (int i = 0; i < 4; ++i) pmax[i] = -INFINITY;
#pragma unroll
    for (int i = 0; i < 4; ++i)
#pragma unroll
      for (int jj = 0; jj < 4; ++jj) {
        int vv = vb + tn * 4 + jj;
        if (vv < NVOC) {
          float z = acc[i][jj];
          float cp = 15.f * z * rsqrtf(z * z + 225.f);
          capv[i][jj] = cp;
          pmax[i] = fmaxf(pmax[i], cp);
          if (vv == tg[i]) tcap[tb * 64 + tm * 4 + i] = cp;
        } else capv[i][jj] = -INFINITY;
      }
#pragma unroll
    for (int i = 0; i < 4; ++i) redm[tm * 4 + i][tn] = pmax[i];
    __syncthreads();
    if (tid < 64) {
      float m = redm[tid][0];
#pragma unroll
      for (int t = 1; t < 16; ++t) m = fmaxf(m, redm[tid][t]);
      rtm[tid] = m;
    }
    __syncthreads();
    float psum[4];
#pragma unroll
    for (int i = 0; i < 4; ++i) {
      float m = rtm[tm * 4 + i];
      float sacc = 0.f;
#pragma unroll
      for (int jj = 0; jj < 4; ++jj) sacc += __expf(capv[i][jj] - m);
      psum[i] = sacc;
    }
    __syncthreads();
#pragma unroll
    for (int i = 0; i < 4; ++i) redm[tm * 4 + i][tn] = psum[i];
    __syncthreads();
    if (tid < 64) {
      float sm = 0.f;
#pragma unroll
      for (int t = 0; t < 16; ++t) sm += redm[tid][t];
      float mo = rowm[tid], mt = rtm[tid];
      float mn = fmaxf(mo, mt);
      rowl[tid] = rowl[tid] * __expf(mo - mn) + sm * __expf(mt - mn);
      rowm[tid] = mn;
    }
    __syncthreads();
  }
  if (tid < 64) {
    part_m[(size_t)ch * NSEQ + tb * 64 + tid] = rowm[tid];
    part_l[(size_t)ch * NSEQ + tb * 64 + tid] = rowl[tid];
  }
}

// ---------------- final loss reduce ----------------
__global__ __launch_bounds__(256) void loss_kernel(const float* __restrict__ part_m, const float* __restrict__ part_l,
                                                   const float* __restrict__ tcap, float* __restrict__ out) {
  int tid = threadIdx.x;
  float sum = 0.f;
  for (int t = tid; t < NSEQ; t += 256) {
    float M = -INFINITY;
    for (int c = 0; c < NCHUNK; ++c) M = fmaxf(M, part_m[(size_t)c * NSEQ + t]);
    float Lq = 0.f;
    for (int c = 0; c < NCHUNK; ++c) Lq += part_l[(size_t)c * NSEQ + t] * __expf(part_m[(size_t)c * NSEQ + t] - M);
    sum += (M + logf(Lq)) - tcap[t];
  }
  __shared__ float red[256];
  red[tid] = sum; __syncthreads();
  for (int o = 128; o > 0; o >>= 1) { if (tid < o) red[tid] += red[tid + o]; __syncthreads(); }
  if (tid == 0) out[0] = red[0] / (float)NSEQ;
}

// ---------------- host driver ----------------
extern "C" void kernel_launch(void* const* d_in, const int* in_sizes, int n_in,
                              void* d_out, int out_size, void* d_ws, size_t ws_size,
                              hipStream_t stream) {
  const int* seq   = (const int*)d_in[0];
  const int* wnb   = (const int*)d_in[1];
  const int* tgt   = (const int*)d_in[2];
  const float* embed = (const float*)d_in[3];
  const float* vemb  = (const float*)d_in[4];
  const float* qkvw  = (const float*)d_in[5];
  const float* aprj  = (const float*)d_in[6];
  const float* fcw   = (const float*)d_in[7];
  const float* prjw  = (const float*)d_in[8];
  const float* scal  = (const float*)d_in[9];
  float* out = (float*)d_out;

  char* w = (char*)d_ws;
  auto alloc = [&](size_t bytes) {
    char* p = w;
    w += (bytes + 255) & ~(size_t)255;
    return p;
  };
  // total ~114 MB of workspace
  int* docs = (int*)alloc(NSEQ * 4);
  int* catL = (int*)alloc(NBLK * NBLK * 4);
  int* catS = (int*)alloc(NBLK * NBLK * 4);
  float* x    = (float*)alloc((size_t)NSEQ * NDIM * 4);
  float* x0   = (float*)alloc((size_t)NSEQ * NDIM * 4);
  float* xa   = (float*)alloc((size_t)NSEQ * NDIM * 4);
  float* sk1  = (float*)alloc((size_t)NSEQ * NDIM * 4);
  float* sk2  = (float*)alloc((size_t)NSEQ * NDIM * 4);
  float* sk3  = (float*)alloc((size_t)NSEQ * NDIM * 4);
  float* qkvb = (float*)alloc((size_t)NSEQ * 3 * NHEAD * NHD * 4);
  float* qb   = (float*)alloc((size_t)NHEAD * NSEQ * NHD * 4);
  float* kb   = (float*)alloc((size_t)NHEAD * NSEQ * NHD * 4);
  float* vb   = (float*)alloc((size_t)NHEAD * NSEQ * NHD * 4);
  float* yb   = (float*)alloc((size_t)NSEQ * NDIM * 4);
  float* hb   = (float*)alloc((size_t)NSEQ * 4 * NDIM * 4);
  float* xf   = (float*)alloc((size_t)NSEQ * NDIM * 4);
  float* pm   = (float*)alloc((size_t)NCHUNK * NSEQ * 4);
  float* pl   = (float*)alloc((size_t)NCHUNK * NSEQ * 4);
  float* tc   = (float*)alloc((size_t)NSEQ * 4);
  float* skips[4] = {nullptr, sk1, sk2, sk3};

  prep_kernel<<<1, 1024, 0, stream>>>(seq, wnb, docs, catL, catS);
  embed_rms_kernel<<<NSEQ, 256, 0, stream>>>(seq, embed, x, x0);

  const int velist[NLAY]   = {0, 1, 2, -1, -1, 0, 1, 2};
  const int skipj[NLAY]    = {-1, -1, -1, -1, -1, 3, 2, 1};
  const int maskLong[NLAY] = {1, 0, 0, 0, 1, 0, 0, 1};

  for (int i = 0; i < NLAY; ++i) {
    mix_kernel<<<1024, 256, 0, stream>>>(x, x0, skipj[i] >= 0 ? skips[skipj[i]] : nullptr, scal, i, skipj[i]);
    rms_kernel<<<NSEQ, 256, 0, stream>>>(x, xa);
    gemm64<0><<<dim3(NSEQ / 64, (3 * NHEAD * NHD) / 64), 256, 0, stream>>>(
        xa, qkvw + (size_t)i * 3 * NHEAD * NHD * NDIM, qkvb, 3 * NHEAD * NHD, NDIM);
    qkv_post_kernel<<<NSEQ, 128, 0, stream>>>(qkvb, vemb, seq, scal, i, velist[i], qb, kb, vb);
    attn_kernel<<<dim3(NSEQ / 32, NHEAD), 128, 0, stream>>>(qb, kb, vb, maskLong[i] ? catL : catS, docs, yb);
    gemm64<1><<<dim3(NSEQ / 64, NDIM / 64), 256, 0, stream>>>(
        yb, aprj + (size_t)i * NDIM * NDIM, x, NDIM, NDIM);
    rms_kernel<<<NSEQ, 256, 0, stream>>>(x, xa);
    gemm64<2><<<dim3(NSEQ / 64, (4 * NDIM) / 64), 256, 0, stream>>>(
        xa, fcw + (size_t)i * 4 * NDIM * NDIM, hb, 4 * NDIM, NDIM);
    gemm64<1><<<dim3(NSEQ / 64, NDIM / 64), 256, 0, stream>>>(
        hb, prjw + (size_t)i * NDIM * 4 * NDIM, x, NDIM, 4 * NDIM);
    if (i >= 1 && i <= 3) {
      hipMemcpyAsync(skips[i], x, (size_t)NSEQ * NDIM * 4, hipMemcpyDeviceToDevice, stream);
    }
  }

  rms_kernel<<<NSEQ, 256, 0, stream>>>(x, xf);
  logits_lse_kernel<<<dim3(NSEQ / 64, NCHUNK), 256, 0, stream>>>(xf, embed, tgt, pm, pl, tc);
  loss_kernel<<<1, 256, 0, stream>>>(pm, pl, tc, out);
}

// Round 2
// 7590.484 us; speedup vs baseline: 1.2606x; 1.2606x over previous
//
#include <hip/hip_runtime.h>
#include <hip/hip_bf16.h>
#include <math.h>

#define NSEQ 2048
#define NDIM 768
#define NLAY 8
#define NHEAD 6
#define NHD 128
#define NVOC 50257
#define NBLK 16
#define BLKSZ 128
#define EOS_TOK 50256
#define EPSF 1.1920929e-07f
#define ASCALE 0.12f
#define VCHUNK 2048
#define NCHUNK 25

using bf16x8 = __attribute__((ext_vector_type(8))) __bf16;
using bf16x4 = __attribute__((ext_vector_type(4))) __bf16;
using f32x4  = __attribute__((ext_vector_type(4))) float;

__device__ __forceinline__ float bf16r(float x) {
  return __bfloat162float(__float2bfloat16(x));
}
__device__ __forceinline__ __bf16 tobf(float x) {
  __hip_bfloat16 h = __float2bfloat16(x);
  return *reinterpret_cast<__bf16*>(&h);
}

// ---------------- prep: docs cumsum + block mask categories ----------------
__global__ __launch_bounds__(1024) void prep_kernel(const int* __restrict__ seq, const int* __restrict__ wptr,
                                                    int* __restrict__ docs, int* __restrict__ catL,
                                                    int* __restrict__ catS) {
  __shared__ int f[NSEQ];
  __shared__ int g[NSEQ];
  int tid = threadIdx.x;
  for (int i = tid; i < NSEQ; i += 1024) f[i] = (seq[i] == EOS_TOK) ? 1 : 0;
  __syncthreads();
  int* a = f; int* b = g;
  for (int off = 1; off < NSEQ; off <<= 1) {
    for (int i = tid; i < NSEQ; i += 1024) {
      int v = a[i];
      if (i >= off) v += a[i - off];
      b[i] = v;
    }
    __syncthreads();
    int* t = a; a = b; b = t;
  }
  for (int i = tid; i < NSEQ; i += 1024) docs[i] = a[i];
  __syncthreads();
  if (tid == 0) {
    int dl[NBLK], dh[NBLK];
    for (int bi = 0; bi < NBLK; ++bi) { dl[bi] = a[bi * BLKSZ]; dh[bi] = a[bi * BLKSZ + BLKSZ - 1]; }
    int W = *wptr;
    for (int pass = 0; pass < 2; ++pass) {
      int w = (pass == 0) ? W : (W / 2);
      int* cat = (pass == 0) ? catL : catS;
      for (int i = 0; i < NBLK; ++i) {
        int allr[NBLK], partr[NBLK];
        int nf = 0, np = 0;
        for (int j = 0; j < NBLK; ++j) {
          int any_ = (i >= j) && (dl[i] <= dh[j]) && (dh[i] >= dl[j]);
          int all_ = (i > j) && (dl[i] == dh[j]) && (dh[i] == dl[j]);
          allr[j] = all_; partr[j] = any_ && !all_;
          nf += all_; np += partr[j];
        }
        int kcf = min(nf, w - 1);
        int kcp = min(np, max(w - nf, 1));
        int cf = 0, cp = 0;
        for (int j = NBLK - 1; j >= 0; --j) {
          int cv = 0;
          if (allr[j]) { cf++; if (cf <= kcf) cv = 2; }
          if (partr[j]) { cp++; if (cp <= kcp) cv = 1; }
          cat[i * NBLK + j] = cv;
        }
      }
    }
  }
}

// ---------------- embedding gather + rms -> x, x0 ----------------
__global__ __launch_bounds__(256) void embed_rms_kernel(const int* __restrict__ seq, const float* __restrict__ embed,
                                                        float* __restrict__ x, float* __restrict__ x0) {
  int s = blockIdx.x;
  int tid = threadIdx.x;
  const float* row = embed + (size_t)seq[s] * NDIM;
  float v0 = row[tid], v1 = row[tid + 256], v2 = row[tid + 512];
  float ss = v0 * v0 + v1 * v1 + v2 * v2;
  __shared__ float red[256];
  red[tid] = ss; __syncthreads();
  for (int o = 128; o > 0; o >>= 1) { if (tid < o) red[tid] += red[tid + o]; __syncthreads(); }
  float sc = rsqrtf(red[0] / (float)NDIM + EPSF);
  size_t base = (size_t)s * NDIM;
  float o0 = v0 * sc, o1 = v1 * sc, o2 = v2 * sc;
  x[base + tid] = o0; x[base + tid + 256] = o1; x[base + tid + 512] = o2;
  x0[base + tid] = o0; x0[base + tid + 256] = o1; x0[base + tid + 512] = o2;
}

// ---------------- row rms: xa = rms(x) ----------------
__global__ __launch_bounds__(256) void rms_kernel(const float* __restrict__ x, float* __restrict__ xa) {
  int s = blockIdx.x;
  int tid = threadIdx.x;
  size_t base = (size_t)s * NDIM;
  float v0 = x[base + tid], v1 = x[base + tid + 256], v2 = x[base + tid + 512];
  float ss = v0 * v0 + v1 * v1 + v2 * v2;
  __shared__ float red[256];
  red[tid] = ss; __syncthreads();
  for (int o = 128; o > 0; o >>= 1) { if (tid < o) red[tid] += red[tid + o]; __syncthreads(); }
  float sc = rsqrtf(red[0] / (float)NDIM + EPSF);
  xa[base + tid] = v0 * sc; xa[base + tid + 256] = v1 * sc; xa[base + tid + 512] = v2 * sc;
}

// ---------------- final rms + bf16 cast ----------------
__global__ __launch_bounds__(256) void rmsbf_kernel(const float* __restrict__ x, __bf16* __restrict__ xb) {
  int s = blockIdx.x;
  int tid = threadIdx.x;
  size_t base = (size_t)s * NDIM;
  float v0 = x[base + tid], v1 = x[base + tid + 256], v2 = x[base + tid + 512];
  float ss = v0 * v0 + v1 * v1 + v2 * v2;
  __shared__ float red[256];
  red[tid] = ss; __syncthreads();
  for (int o = 128; o > 0; o >>= 1) { if (tid < o) red[tid] += red[tid + o]; __syncthreads(); }
  float sc = rsqrtf(red[0] / (float)NDIM + EPSF);
  xb[base + tid] = tobf(v0 * sc); xb[base + tid + 256] = tobf(v1 * sc); xb[base + tid + 512] = tobf(v2 * sc);
}

// ---------------- residual mix: x = lam0*(x + sw*skip) + lam1*x0 ----------------
__global__ __launch_bounds__(256) void mix_kernel(float* __restrict__ x, const float* __restrict__ x0,
                                                  const float* __restrict__ skip, const float* __restrict__ scal,
                                                  int li, int sj) {
  float lam0 = scal[NLAY + 2 * li], lam1 = scal[NLAY + 2 * li + 1];
  float sw = (sj >= 0) ? scal[sj] : 0.f;
  int n4 = NSEQ * NDIM / 4;
  float4* x4 = (float4*)x;
  const float4* o4 = (const float4*)x0;
  const float4* s4 = (const float4*)skip;
  for (int i = blockIdx.x * blockDim.x + threadIdx.x; i < n4; i += gridDim.x * blockDim.x) {
    float4 xv = x4[i];
    float4 ov = o4[i];
    if (skip) {
      float4 sv = s4[i];
      xv.x += sw * sv.x; xv.y += sw * sv.y; xv.z += sw * sv.z; xv.w += sw * sv.w;
    }
    xv.x = lam0 * xv.x + lam1 * ov.x; xv.y = lam0 * xv.y + lam1 * ov.y;
    xv.z = lam0 * xv.z + lam1 * ov.z; xv.w = lam0 * xv.w + lam1 * ov.w;
    x4[i] = xv;
  }
}

// ---------------- generic f32 GEMM: C[m][n] op= sum_k A[m][k]*B[n][k] ----------------
// MODE 0: store, 1: accumulate into C, 2: relu(acc)^2
template <int MODE>
__global__ __launch_bounds__(256) void gemm64(const float* __restrict__ A, const float* __restrict__ B,
                                              float* __restrict__ C, int N, int K) {
  __shared__ float As[64][17];
  __shared__ float Bs[16][64];
  int bm = blockIdx.x * 64, bn = blockIdx.y * 64;
  int tid = threadIdx.x;
  int tm = tid >> 4, tn = tid & 15;
  int lr = tid >> 2, lc = (tid & 3) << 2;
  const float* Ap = A + (size_t)(bm + lr) * K + lc;
  const float* Bp = B + (size_t)(bn + lr) * K + lc;
  float acc[4][4] = {};
  for (int k0 = 0; k0 < K; k0 += 16) {
    float4 av = *(const float4*)(Ap + k0);
    float4 bv = *(const float4*)(Bp + k0);
    As[lr][lc + 0] = av.x; As[lr][lc + 1] = av.y; As[lr][lc + 2] = av.z; As[lr][lc + 3] = av.w;
    Bs[lc + 0][lr] = bv.x; Bs[lc + 1][lr] = bv.y; Bs[lc + 2][lr] = bv.z; Bs[lc + 3][lr] = bv.w;
    __syncthreads();
#pragma unroll
    for (int k = 0; k < 16; ++k) {
      float a0 = As[tm * 4 + 0][k], a1 = As[tm * 4 + 1][k], a2 = As[tm * 4 + 2][k], a3 = As[tm * 4 + 3][k];
      float4 bq = *(const float4*)&Bs[k][tn * 4];
      acc[0][0] += a0 * bq.x; acc[0][1] += a0 * bq.y; acc[0][2] += a0 * bq.z; acc[0][3] += a0 * bq.w;
      acc[1][0] += a1 * bq.x; acc[1][1] += a1 * bq.y; acc[1][2] += a1 * bq.z; acc[1][3] += a1 * bq.w;
      acc[2][0] += a2 * bq.x; acc[2][1] += a2 * bq.y; acc[2][2] += a2 * bq.z; acc[2][3] += a2 * bq.w;
      acc[3][0] += a3 * bq.x; acc[3][1] += a3 * bq.y; acc[3][2] += a3 * bq.z; acc[3][3] += a3 * bq.w;
    }
    __syncthreads();
  }
#pragma unroll
  for (int i = 0; i < 4; ++i)
#pragma unroll
    for (int j = 0; j < 4; ++j) {
      size_t ci = (size_t)(bm + tm * 4 + i) * N + (bn + tn * 4 + j);
      if (MODE == 0) C[ci] = acc[i][j];
      else if (MODE == 1) C[ci] += acc[i][j];
      else { float r = fmaxf(acc[i][j], 0.f); C[ci] = r * r; }
    }
}

// ---------------- qkv post: per-head rms + rope for q,k; value mix for v ----------------
__global__ __launch_bounds__(128) void qkv_post_kernel(const float* __restrict__ qkv, const float* __restrict__ vemb,
                                                       const int* __restrict__ seq, const float* __restrict__ scal,
                                                       int li, int ve_idx,
                                                       float* __restrict__ qo, float* __restrict__ ko,
                                                       float* __restrict__ vo) {
  int s = blockIdx.x;
  int d = threadIdx.x;
  __shared__ float red[128];
  __shared__ float qn[128], kn[128];
  float sal0 = scal[3 * NLAY + 2 * li], sal1 = scal[3 * NLAY + 2 * li + 1];
  int j = d & 63;
  float fr = (j < 32) ? powf(1.0f / 1024.0f, (float)j * (1.0f / 31.0f)) : 0.f;
  float th = (float)s * fr;
  float cth = cosf(th), sth = sinf(th);
  int tok = seq[s];
  for (int h = 0; h < NHEAD; ++h) {
    size_t rb = (size_t)s * (3 * NHEAD * NHD);
    float qv = qkv[rb + h * NHD + d];
    float kv = qkv[rb + NHEAD * NHD + h * NHD + d];
    float vv = qkv[rb + 2 * NHEAD * NHD + h * NHD + d];
    red[d] = qv * qv; __syncthreads();
    for (int o = 64; o > 0; o >>= 1) { if (d < o) red[d] += red[d + o]; __syncthreads(); }
    float sq = red[0]; __syncthreads();
    red[d] = kv * kv; __syncthreads();
    for (int o = 64; o > 0; o >>= 1) { if (d < o) red[d] += red[d + o]; __syncthreads(); }
    float sk = red[0]; __syncthreads();
    qn[d] = qv * rsqrtf(sq / (float)NHD + EPSF);
    kn[d] = kv * rsqrtf(sk / (float)NHD + EPSF);
    __syncthreads();
    float oq, ok;
    if (d < 64) { oq = qn[d] * cth + qn[d + 64] * sth; ok = kn[d] * cth + kn[d + 64] * sth; }
    else        { oq = -qn[j] * sth + qn[j + 64] * cth; ok = -kn[j] * sth + kn[j + 64] * cth; }
    float ov = sal0 * vv;
    if (ve_idx >= 0) ov += sal1 * vemb[((size_t)ve_idx * NVOC + tok) * NDIM + h * NHD + d];
    size_t oo = ((size_t)h * NSEQ + s) * NHD + d;
    qo[oo] = oq; ko[oo] = ok; vo[oo] = ov;
    __syncthreads();
  }
}

// ---------------- flash attention with block-category masks ----------------
__global__ __launch_bounds__(128) void attn_kernel(const float* __restrict__ q, const float* __restrict__ k,
                                                   const float* __restrict__ v, const int* __restrict__ cat,
                                                   const int* __restrict__ docs, float* __restrict__ y) {
  int qb = blockIdx.x;
  int h = blockIdx.y;
  int tid = threadIdx.x;
  int r = tid >> 2;
  int qt = tid & 3;
  int rg = qb * 32 + r;
  int qB = qb >> 2;
  __shared__ float Ks[32][NHD];
  __shared__ float Vs[32][NHD];
  __shared__ int kd[32];
  const float4* qp = (const float4*)(q + ((size_t)h * NSEQ + rg) * NHD + qt * 32);
  float4 qv[8];
#pragma unroll
  for (int i = 0; i < 8; ++i) qv[i] = qp[i];
  float acc[32];
#pragma unroll
  for (int i = 0; i < 32; ++i) acc[i] = 0.f;
  float mrun = -INFINITY, lrun = 0.f;
  int mydoc = docs[rg];
  int nkb = (qB + 1) * (BLKSZ / 32);
  for (int kb = 0; kb < nkb; ++kb) {
    int c = cat[qB * NBLK + (kb >> 2)];
    if (c == 0) continue;
    __syncthreads();
    {
      const float4* ksrc = (const float4*)(k + ((size_t)h * NSEQ + kb * 32) * NHD);
      const float4* vsrc = (const float4*)(v + ((size_t)h * NSEQ + kb * 32) * NHD);
      float4* kdst = (float4*)&Ks[0][0];
      float4* vdst = (float4*)&Vs[0][0];
      for (int i = tid; i < 32 * NHD / 4; i += 128) { kdst[i] = ksrc[i]; vdst[i] = vsrc[i]; }
      if (tid < 32) kd[tid] = docs[kb * 32 + tid];
    }
    __syncthreads();
    float sc[32];
#pragma unroll
    for (int kk = 0; kk < 32; ++kk) {
      const float4* kp = (const float4*)&Ks[kk][qt * 32];
      float sa = 0.f;
#pragma unroll
      for (int i = 0; i < 8; ++i) {
        float4 aa = qv[i], bb = kp[i];
        sa += aa.x * bb.x + aa.y * bb.y + aa.z * bb.z + aa.w * bb.w;
      }
      sa += __shfl_xor(sa, 1, 64);
      sa += __shfl_xor(sa, 2, 64);
      int kg = kb * 32 + kk;
      bool okm = (c == 2) || ((kg <= rg) && (kd[kk] == mydoc));
      sc[kk] = okm ? sa * ASCALE : -INFINITY;
    }
    float bmx = sc[0];
#pragma unroll
    for (int kk = 1; kk < 32; ++kk) bmx = fmaxf(bmx, sc[kk]);
    float mnew = fmaxf(mrun, bmx);
    if (mnew == -INFINITY) continue;
    float corr = __expf(mrun - mnew);
    lrun *= corr;
#pragma unroll
    for (int i = 0; i < 32; ++i) acc[i] *= corr;
#pragma unroll
    for (int kk = 0; kk < 32; ++kk) {
      float p = __expf(sc[kk] - mnew);
      lrun += p;
      const float* vp = &Vs[kk][qt * 32];
#pragma unroll
      for (int i = 0; i < 32; ++i) acc[i] += p * vp[i];
    }
    mrun = mnew;
  }
  float inv = 1.f / lrun;
  float* yo = y + (size_t)rg * (NHEAD * NHD) + h * NHD + qt * 32;
#pragma unroll
  for (int i = 0; i < 32; ++i) yo[i] = acc[i] * inv;
}

// ---------------- MFMA logits + soft-cap + online logsumexp per vocab chunk ----------------
// grid (NSEQ/64, NCHUNK), 256 threads = 4 waves. Wave w owns token rows tb*64+w*16..+15.
__global__ __launch_bounds__(256) void logits_mfma_kernel(const __bf16* __restrict__ xbf,
                                                          const float* __restrict__ embed,
                                                          const int* __restrict__ target,
                                                          float* __restrict__ part_m, float* __restrict__ part_l,
                                                          float* __restrict__ tcap) {
  int tb = blockIdx.x;
  int ch = blockIdx.y;
  int tid = threadIdx.x;
  int w = tid >> 6;
  int l = tid & 63;
  int c = l & 15;        // mfma col / A row
  int g = l >> 4;        // k-group / D row-group
  int kb = g * 8;

  __shared__ __bf16 Bs[64][136];  // padded stride: 272B = 16*17 -> conflict-free b128 reads

  // A fragments: 16 rows of xbf for this wave, all K=768, in registers.
  const __bf16* xrow = xbf + (size_t)(tb * 64 + w * 16 + c) * NDIM + kb;
  bf16x8 afrag[24];
#pragma unroll
  for (int kc = 0; kc < 24; ++kc) afrag[kc] = *(const bf16x8*)(xrow + kc * 32);

  // targets for the 4 rows this lane reduces (row = g*4 + rr)
  int tgv[4];
#pragma unroll
  for (int rr = 0; rr < 4; ++rr) tgv[rr] = target[tb * 64 + w * 16 + g * 4 + rr];

  float rowm[4], rowl[4];
#pragma unroll
  for (int rr = 0; rr < 4; ++rr) { rowm[rr] = -INFINITY; rowl[rr] = 0.f; }

  int srow = tid >> 2;            // staging: row 0..63
  int scol = (tid & 3) * 32;      // staging: col base

  for (int vt = 0; vt < VCHUNK / 64; ++vt) {
    int vb0 = ch * VCHUNK + vt * 64;
    if (vb0 >= NVOC) break;
    f32x4 acc[4] = {f32x4{0.f, 0.f, 0.f, 0.f}, f32x4{0.f, 0.f, 0.f, 0.f},
                    f32x4{0.f, 0.f, 0.f, 0.f}, f32x4{0.f, 0.f, 0.f, 0.f}};
#pragma unroll
    for (int kc = 0; kc < 6; ++kc) {
      __syncthreads();
      {
        int vrow = vb0 + srow;
        bool okr = vrow < NVOC;
        const float* src = embed + (size_t)vrow * NDIM + kc * 128 + scol;
#pragma unroll
        for (int i = 0; i < 8; ++i) {
          float4 fv = okr ? *(const float4*)(src + i * 4) : make_float4(0.f, 0.f, 0.f, 0.f);
          bf16x4 bv;
          bv[0] = tobf(fv.x); bv[1] = tobf(fv.y); bv[2] = tobf(fv.z); bv[3] = tobf(fv.w);
          *(bf16x4*)&Bs[srow][scol + i * 4] = bv;
        }
      }
      __syncthreads();
#pragma unroll
      for (int ks = 0; ks < 4; ++ks) {
        int kk = ks * 32 + kb;
#pragma unroll
        for (int nt = 0; nt < 4; ++nt) {
          bf16x8 bfr = *(const bf16x8*)&Bs[nt * 16 + c][kk];
          acc[nt] = __builtin_amdgcn_mfma_f32_16x16x32_bf16(afrag[kc * 4 + ks], bfr, acc[nt], 0, 0, 0);
        }
      }
    }
    // epilogue: soft-cap, target grab, per-row online (max, sumexp)
    float cap[4][4];  // [nt][rr]
    float tmax[4];
#pragma unroll
    for (int rr = 0; rr < 4; ++rr) tmax[rr] = -INFINITY;
#pragma unroll
    for (int nt = 0; nt < 4; ++nt) {
      int vv = vb0 + nt * 16 + c;
      bool okv = vv < NVOC;
#pragma unroll
      for (int rr = 0; rr < 4; ++rr) {
        float z = acc[nt][rr];
        float cp = okv ? 15.f * z * rsqrtf(z * z + 225.f) : -INFINITY;
        cap[nt][rr] = cp;
        tmax[rr] = fmaxf(tmax[rr], cp);
        if (okv && vv == tgv[rr]) tcap[tb * 64 + w * 16 + g * 4 + rr] = cp;
      }
    }
#pragma unroll
    for (int rr = 0; rr < 4; ++rr) {
      tmax[rr] = fmaxf(tmax[rr], __shfl_xor(tmax[rr], 1, 64));
      tmax[rr] = fmaxf(tmax[rr], __shfl_xor(tmax[rr], 2, 64));
      tmax[rr] = fmaxf(tmax[rr], __shfl_xor(tmax[rr], 4, 64));
      tmax[rr] = fmaxf(tmax[rr], __shfl_xor(tmax[rr], 8, 64));
    }
    float tsum[4];
#pragma unroll
    for (int rr = 0; rr < 4; ++rr) {
      float s = 0.f;
#pragma unroll
      for (int nt = 0; nt < 4; ++nt) s += __expf(cap[nt][rr] - tmax[rr]);
      s += __shfl_xor(s, 1, 64);
      s += __shfl_xor(s, 2, 64);
      s += __shfl_xor(s, 4, 64);
      s += __shfl_xor(s, 8, 64);
      tsum[rr] = s;
    }
#pragma unroll
    for (int rr = 0; rr < 4; ++rr) {
      float mn = fmaxf(rowm[rr], tmax[rr]);
      rowl[rr] = rowl[rr] * __expf(rowm[rr] - mn) + tsum[rr] * __expf(tmax[rr] - mn);
      rowm[rr] = mn;
    }
  }
  if (c == 0) {
#pragma unroll
    for (int rr = 0; rr < 4; ++rr) {
      int row = tb * 64 + w * 16 + g * 4 + rr;
      part_m[(size_t)ch * NSEQ + row] = rowm[rr];
      part_l[(size_t)ch * NSEQ + row] = rowl[rr];
    }
  }
}

// ---------------- final loss reduce ----------------
__global__ __launch_bounds__(256) void loss_kernel(const float* __restrict__ part_m, const float* __restrict__ part_l,
                                                   const float* __restrict__ tcap, float* __restrict__ out) {
  int tid = threadIdx.x;
  float sum = 0.f;
  for (int t = tid; t < NSEQ; t += 256) {
    float M = -INFINITY;
    for (int cc = 0; cc < NCHUNK; ++cc) M = fmaxf(M, part_m[(size_t)cc * NSEQ + t]);
    float Lq = 0.f;
    for (int cc = 0; cc < NCHUNK; ++cc) Lq += part_l[(size_t)cc * NSEQ + t] * __expf(part_m[(size_t)cc * NSEQ + t] - M);
    sum += (M + logf(Lq)) - tcap[t];
  }
  __shared__ float red[256];
  red[tid] = sum; __syncthreads();
  for (int o = 128; o > 0; o >>= 1) { if (tid < o) red[tid] += red[tid + o]; __syncthreads(); }
  if (tid == 0) out[0] = red[0] / (float)NSEQ;
}

// ---------------- host driver ----------------
extern "C" void kernel_launch(void* const* d_in, const int* in_sizes, int n_in,
                              void* d_out, int out_size, void* d_ws, size_t ws_size,
                              hipStream_t stream) {
  const int* seq   = (const int*)d_in[0];
  const int* wnb   = (const int*)d_in[1];
  const int* tgt   = (const int*)d_in[2];
  const float* embed = (const float*)d_in[3];
  const float* vemb  = (const float*)d_in[4];
  const float* qkvw  = (const float*)d_in[5];
  const float* aprj  = (const float*)d_in[6];
  const float* fcw   = (const float*)d_in[7];
  const float* prjw  = (const float*)d_in[8];
  const float* scal  = (const float*)d_in[9];
  float* out = (float*)d_out;

  char* w = (char*)d_ws;
  auto alloc = [&](size_t bytes) {
    char* p = w;
    w += (bytes + 255) & ~(size_t)255;
    return p;
  };
  int* docs = (int*)alloc(NSEQ * 4);
  int* catL = (int*)alloc(NBLK * NBLK * 4);
  int* catS = (int*)alloc(NBLK * NBLK * 4);
  float* x    = (float*)alloc((size_t)NSEQ * NDIM * 4);
  float* x0   = (float*)alloc((size_t)NSEQ * NDIM * 4);
  float* xa   = (float*)alloc((size_t)NSEQ * NDIM * 4);
  float* sk1  = (float*)alloc((size_t)NSEQ * NDIM * 4);
  float* sk2  = (float*)alloc((size_t)NSEQ * NDIM * 4);
  float* sk3  = (float*)alloc((size_t)NSEQ * NDIM * 4);
  float* qkvb = (float*)alloc((size_t)NSEQ * 3 * NHEAD * NHD * 4);
  float* qb   = (float*)alloc((size_t)NHEAD * NSEQ * NHD * 4);
  float* kb   = (float*)alloc((size_t)NHEAD * NSEQ * NHD * 4);
  float* vb   = (float*)alloc((size_t)NHEAD * NSEQ * NHD * 4);
  float* yb   = (float*)alloc((size_t)NSEQ * NDIM * 4);
  float* hb   = (float*)alloc((size_t)NSEQ * 4 * NDIM * 4);
  __bf16* xbf = (__bf16*)alloc((size_t)NSEQ * NDIM * 2);
  float* pm   = (float*)alloc((size_t)NCHUNK * NSEQ * 4);
  float* pl   = (float*)alloc((size_t)NCHUNK * NSEQ * 4);
  float* tc   = (float*)alloc((size_t)NSEQ * 4);
  float* skips[4] = {nullptr, sk1, sk2, sk3};

  prep_kernel<<<1, 1024, 0, stream>>>(seq, wnb, docs, catL, catS);
  embed_rms_kernel<<<NSEQ, 256, 0, stream>>>(seq, embed, x, x0);

  const int velist[NLAY]   = {0, 1, 2, -1, -1, 0, 1, 2};
  const int skipj[NLAY]    = {-1, -1, -1, -1, -1, 3, 2, 1};
  const int maskLong[NLAY] = {1, 0, 0, 0, 1, 0, 0, 1};

  for (int i = 0; i < NLAY; ++i) {
    mix_kernel<<<1024, 256, 0, stream>>>(x, x0, skipj[i] >= 0 ? skips[skipj[i]] : nullptr, scal, i, skipj[i]);
    rms_kernel<<<NSEQ, 256, 0, stream>>>(x, xa);
    gemm64<0><<<dim3(NSEQ / 64, (3 * NHEAD * NHD) / 64), 256, 0, stream>>>(
        xa, qkvw + (size_t)i * 3 * NHEAD * NHD * NDIM, qkvb, 3 * NHEAD * NHD, NDIM);
    qkv_post_kernel<<<NSEQ, 128, 0, stream>>>(qkvb, vemb, seq, scal, i, velist[i], qb, kb, vb);
    attn_kernel<<<dim3(NSEQ / 32, NHEAD), 128, 0, stream>>>(qb, kb, vb, maskLong[i] ? catL : catS, docs, yb);
    gemm64<1><<<dim3(NSEQ / 64, NDIM / 64), 256, 0, stream>>>(
        yb, aprj + (size_t)i * NDIM * NDIM, x, NDIM, NDIM);
    rms_kernel<<<NSEQ, 256, 0, stream>>>(x, xa);
    gemm64<2><<<dim3(NSEQ / 64, (4 * NDIM) / 64), 256, 0, stream>>>(
        xa, fcw + (size_t)i * 4 * NDIM * NDIM, hb, 4 * NDIM, NDIM);
    gemm64<1><<<dim3(NSEQ / 64, NDIM / 64), 256, 0, stream>>>(
        hb, prjw + (size_t)i * NDIM * 4 * NDIM, x, NDIM, 4 * NDIM);
    if (i >= 1 && i <= 3) {
      hipMemcpyAsync(skips[i], x, (size_t)NSEQ * NDIM * 4, hipMemcpyDeviceToDevice, stream);
    }
  }

  rmsbf_kernel<<<NSEQ, 256, 0, stream>>>(x, xbf);
  logits_mfma_kernel<<<dim3(NSEQ / 64, NCHUNK), 256, 0, stream>>>(xbf, embed, tgt, pm, pl, tc);
  loss_kernel<<<1, 256, 0, stream>>>(pm, pl, tc, out);
}

// Round 3
// 4377.537 us; speedup vs baseline: 2.1859x; 1.7340x over previous
//
#include <hip/hip_runtime.h>
#include <hip/hip_bf16.h>
#include <math.h>

#define NSEQ 2048
#define NDIM 768
#define NLAY 8
#define NHEAD 6
#define NHD 128
#define NVOC 50257
#define NBLK 16
#define BLKSZ 128
#define EOS_TOK 50256
#define EPSF 1.1920929e-07f
#define ASCALE 0.12f
#define VCHUNK 2048
#define NCHUNK 25

using bf16x8 = __attribute__((ext_vector_type(8))) __bf16;
using bf16x4 = __attribute__((ext_vector_type(4))) __bf16;
using f32x4  = __attribute__((ext_vector_type(4))) float;

__device__ __forceinline__ __bf16 tobf(float x) {
  __hip_bfloat16 h = __float2bfloat16(x);
  return *reinterpret_cast<__bf16*>(&h);
}

// ---------------- f32 -> bf16 bulk convert ----------------
__global__ __launch_bounds__(256) void cvt_bf16_kernel(const float* __restrict__ in, __bf16* __restrict__ out,
                                                       long n) {
  long i = ((long)blockIdx.x * blockDim.x + threadIdx.x) * 4;
  long stride = (long)gridDim.x * blockDim.x * 4;
  for (; i < n; i += stride) {
    float4 v = *(const float4*)(in + i);
    bf16x4 o;
    o[0] = tobf(v.x); o[1] = tobf(v.y); o[2] = tobf(v.z); o[3] = tobf(v.w);
    *(bf16x4*)(out + i) = o;
  }
}

// ---------------- prep: docs cumsum + block mask categories ----------------
__global__ __launch_bounds__(1024) void prep_kernel(const int* __restrict__ seq, const int* __restrict__ wptr,
                                                    int* __restrict__ docs, int* __restrict__ catL,
                                                    int* __restrict__ catS) {
  __shared__ int f[NSEQ];
  __shared__ int g[NSEQ];
  int tid = threadIdx.x;
  for (int i = tid; i < NSEQ; i += 1024) f[i] = (seq[i] == EOS_TOK) ? 1 : 0;
  __syncthreads();
  int* a = f; int* b = g;
  for (int off = 1; off < NSEQ; off <<= 1) {
    for (int i = tid; i < NSEQ; i += 1024) {
      int v = a[i];
      if (i >= off) v += a[i - off];
      b[i] = v;
    }
    __syncthreads();
    int* t = a; a = b; b = t;
  }
  for (int i = tid; i < NSEQ; i += 1024) docs[i] = a[i];
  __syncthreads();
  if (tid == 0) {
    int dl[NBLK], dh[NBLK];
    for (int bi = 0; bi < NBLK; ++bi) { dl[bi] = a[bi * BLKSZ]; dh[bi] = a[bi * BLKSZ + BLKSZ - 1]; }
    int W = *wptr;
    for (int pass = 0; pass < 2; ++pass) {
      int w = (pass == 0) ? W : (W / 2);
      int* cat = (pass == 0) ? catL : catS;
      for (int i = 0; i < NBLK; ++i) {
        int allr[NBLK], partr[NBLK];
        int nf = 0, np = 0;
        for (int j = 0; j < NBLK; ++j) {
          int any_ = (i >= j) && (dl[i] <= dh[j]) && (dh[i] >= dl[j]);
          int all_ = (i > j) && (dl[i] == dh[j]) && (dh[i] == dl[j]);
          allr[j] = all_; partr[j] = any_ && !all_;
          nf += all_; np += partr[j];
        }
        int kcf = min(nf, w - 1);
        int kcp = min(np, max(w - nf, 1));
        int cf = 0, cp = 0;
        for (int j = NBLK - 1; j >= 0; --j) {
          int cv = 0;
          if (allr[j]) { cf++; if (cf <= kcf) cv = 2; }
          if (partr[j]) { cp++; if (cp <= kcp) cv = 1; }
          cat[i * NBLK + j] = cv;
        }
      }
    }
  }
}

// ---------------- embedding gather + rms -> x, x0 ----------------
__global__ __launch_bounds__(256) void embed_rms_kernel(const int* __restrict__ seq, const float* __restrict__ embed,
                                                        float* __restrict__ x, float* __restrict__ x0) {
  int s = blockIdx.x;
  int tid = threadIdx.x;
  const float* row = embed + (size_t)seq[s] * NDIM;
  float v0 = row[tid], v1 = row[tid + 256], v2 = row[tid + 512];
  float ss = v0 * v0 + v1 * v1 + v2 * v2;
  __shared__ float red[256];
  red[tid] = ss; __syncthreads();
  for (int o = 128; o > 0; o >>= 1) { if (tid < o) red[tid] += red[tid + o]; __syncthreads(); }
  float sc = rsqrtf(red[0] / (float)NDIM + EPSF);
  size_t base = (size_t)s * NDIM;
  float o0 = v0 * sc, o1 = v1 * sc, o2 = v2 * sc;
  x[base + tid] = o0; x[base + tid + 256] = o1; x[base + tid + 512] = o2;
  x0[base + tid] = o0; x0[base + tid + 256] = o1; x0[base + tid + 512] = o2;
}

// ---------------- row rms -> bf16 ----------------
__global__ __launch_bounds__(256) void rmsbf_kernel(const float* __restrict__ x, __bf16* __restrict__ xb) {
  int s = blockIdx.x;
  int tid = threadIdx.x;
  size_t base = (size_t)s * NDIM;
  float v0 = x[base + tid], v1 = x[base + tid + 256], v2 = x[base + tid + 512];
  float ss = v0 * v0 + v1 * v1 + v2 * v2;
  __shared__ float red[256];
  red[tid] = ss; __syncthreads();
  for (int o = 128; o > 0; o >>= 1) { if (tid < o) red[tid] += red[tid + o]; __syncthreads(); }
  float sc = rsqrtf(red[0] / (float)NDIM + EPSF);
  xb[base + tid] = tobf(v0 * sc); xb[base + tid + 256] = tobf(v1 * sc); xb[base + tid + 512] = tobf(v2 * sc);
}

// ---------------- residual mix: x = lam0*(x + sw*skip) + lam1*x0 ----------------
__global__ __launch_bounds__(256) void mix_kernel(float* __restrict__ x, const float* __restrict__ x0,
                                                  const float* __restrict__ skip, const float* __restrict__ scal,
                                                  int li, int sj) {
  float lam0 = scal[NLAY + 2 * li], lam1 = scal[NLAY + 2 * li + 1];
  float sw = (sj >= 0) ? scal[sj] : 0.f;
  int n4 = NSEQ * NDIM / 4;
  float4* x4 = (float4*)x;
  const float4* o4 = (const float4*)x0;
  const float4* s4 = (const float4*)skip;
  for (int i = blockIdx.x * blockDim.x + threadIdx.x; i < n4; i += gridDim.x * blockDim.x) {
    float4 xv = x4[i];
    float4 ov = o4[i];
    if (skip) {
      float4 sv = s4[i];
      xv.x += sw * sv.x; xv.y += sw * sv.y; xv.z += sw * sv.z; xv.w += sw * sv.w;
    }
    xv.x = lam0 * xv.x + lam1 * ov.x; xv.y = lam0 * xv.y + lam1 * ov.y;
    xv.z = lam0 * xv.z + lam1 * ov.z; xv.w = lam0 * xv.w + lam1 * ov.w;
    x4[i] = xv;
  }
}

// ---------------- bf16 MFMA GEMM: C[m][n] = sum_k A[m][k]*B[n][k] ----------------
// 128x128 tile, 256 threads (4 waves, 2x2), BK=32, padded LDS rows (40 bf16 = 80B).
// MODE 0: store f32; 1: accumulate into f32; 2: relu(acc)^2 -> bf16
template <int MODE>
__global__ __launch_bounds__(256) void gemm_mfma(const __bf16* __restrict__ A, const __bf16* __restrict__ B,
                                                 float* __restrict__ Cf, __bf16* __restrict__ Cb,
                                                 int N, int K) {
  __shared__ __bf16 As[128][40];
  __shared__ __bf16 Bs[128][40];
  int bm = blockIdx.x * 128, bn = blockIdx.y * 128;
  int tid = threadIdx.x;
  int w = tid >> 6, l = tid & 63;
  int wm = (w >> 1) * 64, wn = (w & 1) * 64;
  int c = l & 15, g = l >> 4;
  int srow = tid >> 1, shalf = (tid & 1) * 16;
  const __bf16* Ap = A + (size_t)(bm + srow) * K + shalf;
  const __bf16* Bp = B + (size_t)(bn + srow) * K + shalf;
  f32x4 acc[4][4] = {};
  for (int k0 = 0; k0 < K; k0 += 32) {
    bf16x8 av0 = *(const bf16x8*)(Ap + k0);
    bf16x8 av1 = *(const bf16x8*)(Ap + k0 + 8);
    bf16x8 bv0 = *(const bf16x8*)(Bp + k0);
    bf16x8 bv1 = *(const bf16x8*)(Bp + k0 + 8);
    __syncthreads();
    *(bf16x8*)&As[srow][shalf] = av0; *(bf16x8*)&As[srow][shalf + 8] = av1;
    *(bf16x8*)&Bs[srow][shalf] = bv0; *(bf16x8*)&Bs[srow][shalf + 8] = bv1;
    __syncthreads();
    bf16x8 af[4], bfr[4];
#pragma unroll
    for (int i = 0; i < 4; ++i) af[i] = *(const bf16x8*)&As[wm + i * 16 + c][g * 8];
#pragma unroll
    for (int j = 0; j < 4; ++j) bfr[j] = *(const bf16x8*)&Bs[wn + j * 16 + c][g * 8];
#pragma unroll
    for (int i = 0; i < 4; ++i)
#pragma unroll
      for (int j = 0; j < 4; ++j)
        acc[i][j] = __builtin_amdgcn_mfma_f32_16x16x32_bf16(af[i], bfr[j], acc[i][j], 0, 0, 0);
  }
#pragma unroll
  for (int i = 0; i < 4; ++i)
#pragma unroll
    for (int j = 0; j < 4; ++j)
#pragma unroll
      for (int rr = 0; rr < 4; ++rr) {
        int row = bm + wm + i * 16 + g * 4 + rr;
        int col = bn + wn + j * 16 + c;
        size_t ci = (size_t)row * N + col;
        float z = acc[i][j][rr];
        if (MODE == 0) Cf[ci] = z;
        else if (MODE == 1) Cf[ci] += z;
        else { float r = fmaxf(z, 0.f); Cb[ci] = tobf(r * r); }
      }
}

// ---------------- qkv post: per-head rms + rope for q,k; value mix for v ----------------
__global__ __launch_bounds__(128) void qkv_post_kernel(const float* __restrict__ qkv, const float* __restrict__ vemb,
                                                       const int* __restrict__ seq, const float* __restrict__ scal,
                                                       int li, int ve_idx,
                                                       float* __restrict__ qo, float* __restrict__ ko,
                                                       float* __restrict__ vo) {
  int s = blockIdx.x;
  int d = threadIdx.x;
  __shared__ float red[128];
  __shared__ float qn[128], kn[128];
  float sal0 = scal[3 * NLAY + 2 * li], sal1 = scal[3 * NLAY + 2 * li + 1];
  int j = d & 63;
  float fr = (j < 32) ? powf(1.0f / 1024.0f, (float)j * (1.0f / 31.0f)) : 0.f;
  float th = (float)s * fr;
  float cth = cosf(th), sth = sinf(th);
  int tok = seq[s];
  for (int h = 0; h < NHEAD; ++h) {
    size_t rb = (size_t)s * (3 * NHEAD * NHD);
    float qv = qkv[rb + h * NHD + d];
    float kv = qkv[rb + NHEAD * NHD + h * NHD + d];
    float vv = qkv[rb + 2 * NHEAD * NHD + h * NHD + d];
    red[d] = qv * qv; __syncthreads();
    for (int o = 64; o > 0; o >>= 1) { if (d < o) red[d] += red[d + o]; __syncthreads(); }
    float sq = red[0]; __syncthreads();
    red[d] = kv * kv; __syncthreads();
    for (int o = 64; o > 0; o >>= 1) { if (d < o) red[d] += red[d + o]; __syncthreads(); }
    float sk = red[0]; __syncthreads();
    qn[d] = qv * rsqrtf(sq / (float)NHD + EPSF);
    kn[d] = kv * rsqrtf(sk / (float)NHD + EPSF);
    __syncthreads();
    float oq, ok;
    if (d < 64) { oq = qn[d] * cth + qn[d + 64] * sth; ok = kn[d] * cth + kn[d + 64] * sth; }
    else        { oq = -qn[j] * sth + qn[j + 64] * cth; ok = -kn[j] * sth + kn[j + 64] * cth; }
    float ov = sal0 * vv;
    if (ve_idx >= 0) ov += sal1 * vemb[((size_t)ve_idx * NVOC + tok) * NDIM + h * NHD + d];
    size_t oo = ((size_t)h * NSEQ + s) * NHD + d;
    qo[oo] = oq; ko[oo] = ok; vo[oo] = ov;
    __syncthreads();
  }
}

// ---------------- flash attention with block-category masks (bf16 output) ----------------
__global__ __launch_bounds__(128) void attn_kernel(const float* __restrict__ q, const float* __restrict__ k,
                                                   const float* __restrict__ v, const int* __restrict__ cat,
                                                   const int* __restrict__ docs, __bf16* __restrict__ y) {
  int qb = blockIdx.x;
  int h = blockIdx.y;
  int tid = threadIdx.x;
  int r = tid >> 2;
  int qt = tid & 3;
  int rg = qb * 32 + r;
  int qB = qb >> 2;
  __shared__ float Ks[32][NHD];
  __shared__ float Vs[32][NHD];
  __shared__ int kd[32];
  const float4* qp = (const float4*)(q + ((size_t)h * NSEQ + rg) * NHD + qt * 32);
  float4 qv[8];
#pragma unroll
  for (int i = 0; i < 8; ++i) qv[i] = qp[i];
  float acc[32];
#pragma unroll
  for (int i = 0; i < 32; ++i) acc[i] = 0.f;
  float mrun = -INFINITY, lrun = 0.f;
  int mydoc = docs[rg];
  int nkb = (qB + 1) * (BLKSZ / 32);
  for (int kb = 0; kb < nkb; ++kb) {
    int c = cat[qB * NBLK + (kb >> 2)];
    if (c == 0) continue;
    __syncthreads();
    {
      const float4* ksrc = (const float4*)(k + ((size_t)h * NSEQ + kb * 32) * NHD);
      const float4* vsrc = (const float4*)(v + ((size_t)h * NSEQ + kb * 32) * NHD);
      float4* kdst = (float4*)&Ks[0][0];
      float4* vdst = (float4*)&Vs[0][0];
      for (int i = tid; i < 32 * NHD / 4; i += 128) { kdst[i] = ksrc[i]; vdst[i] = vsrc[i]; }
      if (tid < 32) kd[tid] = docs[kb * 32 + tid];
    }
    __syncthreads();
    float sc[32];
#pragma unroll
    for (int kk = 0; kk < 32; ++kk) {
      const float4* kp = (const float4*)&Ks[kk][qt * 32];
      float sa = 0.f;
#pragma unroll
      for (int i = 0; i < 8; ++i) {
        float4 aa = qv[i], bb = kp[i];
        sa += aa.x * bb.x + aa.y * bb.y + aa.z * bb.z + aa.w * bb.w;
      }
      sa += __shfl_xor(sa, 1, 64);
      sa += __shfl_xor(sa, 2, 64);
      int kg = kb * 32 + kk;
      bool okm = (c == 2) || ((kg <= rg) && (kd[kk] == mydoc));
      sc[kk] = okm ? sa * ASCALE : -INFINITY;
    }
    float bmx = sc[0];
#pragma unroll
    for (int kk = 1; kk < 32; ++kk) bmx = fmaxf(bmx, sc[kk]);
    float mnew = fmaxf(mrun, bmx);
    if (mnew == -INFINITY) continue;
    float corr = __expf(mrun - mnew);
    lrun *= corr;
#pragma unroll
    for (int i = 0; i < 32; ++i) acc[i] *= corr;
#pragma unroll
    for (int kk = 0; kk < 32; ++kk) {
      float p = __expf(sc[kk] - mnew);
      lrun += p;
      const float* vp = &Vs[kk][qt * 32];
#pragma unroll
      for (int i = 0; i < 32; ++i) acc[i] += p * vp[i];
    }
    mrun = mnew;
  }
  float inv = 1.f / lrun;
  __bf16* yo = y + (size_t)rg * (NHEAD * NHD) + h * NHD + qt * 32;
#pragma unroll
  for (int i = 0; i < 32; ++i) yo[i] = tobf(acc[i] * inv);
}

// ---------------- MFMA logits + soft-cap + online logsumexp per vocab chunk ----------------
__global__ __launch_bounds__(256) void logits_mfma_kernel(const __bf16* __restrict__ xbf,
                                                          const __bf16* __restrict__ embed_bf,
                                                          const int* __restrict__ target,
                                                          float* __restrict__ part_m, float* __restrict__ part_l,
                                                          float* __restrict__ tcap) {
  int tb = blockIdx.x;
  int ch = blockIdx.y;
  int tid = threadIdx.x;
  int w = tid >> 6;
  int l = tid & 63;
  int c = l & 15;
  int g = l >> 4;
  int kb = g * 8;

  __shared__ __bf16 Bs[64][136];

  const __bf16* xrow = xbf + (size_t)(tb * 64 + w * 16 + c) * NDIM + kb;
  bf16x8 afrag[24];
#pragma unroll
  for (int kc = 0; kc < 24; ++kc) afrag[kc] = *(const bf16x8*)(xrow + kc * 32);

  int tgv[4];
#pragma unroll
  for (int rr = 0; rr < 4; ++rr) tgv[rr] = target[tb * 64 + w * 16 + g * 4 + rr];

  float rowm[4], rowl[4];
#pragma unroll
  for (int rr = 0; rr < 4; ++rr) { rowm[rr] = -INFINITY; rowl[rr] = 0.f; }

  int srow = tid >> 2;
  int scol = (tid & 3) * 32;

  for (int vt = 0; vt < VCHUNK / 64; ++vt) {
    int vb0 = ch * VCHUNK + vt * 64;
    if (vb0 >= NVOC) break;
    f32x4 acc[4] = {f32x4{0.f, 0.f, 0.f, 0.f}, f32x4{0.f, 0.f, 0.f, 0.f},
                    f32x4{0.f, 0.f, 0.f, 0.f}, f32x4{0.f, 0.f, 0.f, 0.f}};
#pragma unroll
    for (int kc = 0; kc < 6; ++kc) {
      __syncthreads();
      {
        int vrow = vb0 + srow;
        bool okr = vrow < NVOC;
        const __bf16* src = embed_bf + (size_t)vrow * NDIM + kc * 128 + scol;
        bf16x8 zv = {};
#pragma unroll
        for (int i = 0; i < 4; ++i) {
          bf16x8 bv = okr ? *(const bf16x8*)(src + i * 8) : zv;
          *(bf16x8*)&Bs[srow][scol + i * 8] = bv;
        }
      }
      __syncthreads();
#pragma unroll
      for (int ks = 0; ks < 4; ++ks) {
        int kk = ks * 32 + kb;
#pragma unroll
        for (int nt = 0; nt < 4; ++nt) {
          bf16x8 bfr = *(const bf16x8*)&Bs[nt * 16 + c][kk];
          acc[nt] = __builtin_amdgcn_mfma_f32_16x16x32_bf16(afrag[kc * 4 + ks], bfr, acc[nt], 0, 0, 0);
        }
      }
    }
    float cap[4][4];
    float tmax[4];
#pragma unroll
    for (int rr = 0; rr < 4; ++rr) tmax[rr] = -INFINITY;
#pragma unroll
    for (int nt = 0; nt < 4; ++nt) {
      int vv = vb0 + nt * 16 + c;
      bool okv = vv < NVOC;
#pragma unroll
      for (int rr = 0; rr < 4; ++rr) {
        float z = acc[nt][rr];
        float cp = okv ? 15.f * z * rsqrtf(z * z + 225.f) : -INFINITY;
        cap[nt][rr] = cp;
        tmax[rr] = fmaxf(tmax[rr], cp);
        if (okv && vv == tgv[rr]) tcap[tb * 64 + w * 16 + g * 4 + rr] = cp;
      }
    }
#pragma unroll
    for (int rr = 0; rr < 4; ++rr) {
      tmax[rr] = fmaxf(tmax[rr], __shfl_xor(tmax[rr], 1, 64));
      tmax[rr] = fmaxf(tmax[rr], __shfl_xor(tmax[rr], 2, 64));
      tmax[rr] = fmaxf(tmax[rr], __shfl_xor(tmax[rr], 4, 64));
      tmax[rr] = fmaxf(tmax[rr], __shfl_xor(tmax[rr], 8, 64));
    }
    float tsum[4];
#pragma unroll
    for (int rr = 0; rr < 4; ++rr) {
      float s = 0.f;
#pragma unroll
      for (int nt = 0; nt < 4; ++nt) s += __expf(cap[nt][rr] - tmax[rr]);
      s += __shfl_xor(s, 1, 64);
      s += __shfl_xor(s, 2, 64);
      s += __shfl_xor(s, 4, 64);
      s += __shfl_xor(s, 8, 64);
      tsum[rr] = s;
    }
#pragma unroll
    for (int rr = 0; rr < 4; ++rr) {
      float mn = fmaxf(rowm[rr], tmax[rr]);
      rowl[rr] = rowl[rr] * __expf(rowm[rr] - mn) + tsum[rr] * __expf(tmax[rr] - mn);
      rowm[rr] = mn;
    }
  }
  if (c == 0) {
#pragma unroll
    for (int rr = 0; rr < 4; ++rr) {
      int row = tb * 64 + w * 16 + g * 4 + rr;
      part_m[(size_t)ch * NSEQ + row] = rowm[rr];
      part_l[(size_t)ch * NSEQ + row] = rowl[rr];
    }
  }
}

// ---------------- final loss reduce ----------------
__global__ __launch_bounds__(256) void loss_kernel(const float* __restrict__ part_m, const float* __restrict__ part_l,
                                                   const float* __restrict__ tcap, float* __restrict__ out) {
  int tid = threadIdx.x;
  float sum = 0.f;
  for (int t = tid; t < NSEQ; t += 256) {
    float M = -INFINITY;
    for (int cc = 0; cc < NCHUNK; ++cc) M = fmaxf(M, part_m[(size_t)cc * NSEQ + t]);
    float Lq = 0.f;
    for (int cc = 0; cc < NCHUNK; ++cc) Lq += part_l[(size_t)cc * NSEQ + t] * __expf(part_m[(size_t)cc * NSEQ + t] - M);
    sum += (M + logf(Lq)) - tcap[t];
  }
  __shared__ float red[256];
  red[tid] = sum; __syncthreads();
  for (int o = 128; o > 0; o >>= 1) { if (tid < o) red[tid] += red[tid + o]; __syncthreads(); }
  if (tid == 0) out[0] = red[0] / (float)NSEQ;
}

// ---------------- host driver ----------------
extern "C" void kernel_launch(void* const* d_in, const int* in_sizes, int n_in,
                              void* d_out, int out_size, void* d_ws, size_t ws_size,
                              hipStream_t stream) {
  const int* seq   = (const int*)d_in[0];
  const int* wnb   = (const int*)d_in[1];
  const int* tgt   = (const int*)d_in[2];
  const float* embed = (const float*)d_in[3];
  const float* vemb  = (const float*)d_in[4];
  const float* qkvw  = (const float*)d_in[5];
  const float* aprj  = (const float*)d_in[6];
  const float* fcw   = (const float*)d_in[7];
  const float* prjw  = (const float*)d_in[8];
  const float* scal  = (const float*)d_in[9];
  float* out = (float*)d_out;

  char* w = (char*)d_ws;
  auto alloc = [&](size_t bytes) {
    char* p = w;
    w += (bytes + 255) & ~(size_t)255;
    return p;
  };
  int* docs = (int*)alloc(NSEQ * 4);
  int* catL = (int*)alloc(NBLK * NBLK * 4);
  int* catS = (int*)alloc(NBLK * NBLK * 4);
  float* x    = (float*)alloc((size_t)NSEQ * NDIM * 4);
  float* x0   = (float*)alloc((size_t)NSEQ * NDIM * 4);
  float* sk1  = (float*)alloc((size_t)NSEQ * NDIM * 4);
  float* sk2  = (float*)alloc((size_t)NSEQ * NDIM * 4);
  float* sk3  = (float*)alloc((size_t)NSEQ * NDIM * 4);
  float* qkvb = (float*)alloc((size_t)NSEQ * 3 * NHEAD * NHD * 4);
  float* qb   = (float*)alloc((size_t)NHEAD * NSEQ * NHD * 4);
  float* kb   = (float*)alloc((size_t)NHEAD * NSEQ * NHD * 4);
  float* vb   = (float*)alloc((size_t)NHEAD * NSEQ * NHD * 4);
  __bf16* xabf = (__bf16*)alloc((size_t)NSEQ * NDIM * 2);
  __bf16* ybf  = (__bf16*)alloc((size_t)NSEQ * NDIM * 2);
  __bf16* hbf  = (__bf16*)alloc((size_t)NSEQ * 4 * NDIM * 2);
  __bf16* xbf  = (__bf16*)alloc((size_t)NSEQ * NDIM * 2);
  float* pm   = (float*)alloc((size_t)NCHUNK * NSEQ * 4);
  float* pl   = (float*)alloc((size_t)NCHUNK * NSEQ * 4);
  float* tc   = (float*)alloc((size_t)NSEQ * 4);
  __bf16* embbf = (__bf16*)alloc((size_t)NVOC * NDIM * 2);
  __bf16* qkvwbf = (__bf16*)alloc((size_t)NLAY * 3 * NHEAD * NHD * NDIM * 2);
  __bf16* aprjbf = (__bf16*)alloc((size_t)NLAY * NDIM * NDIM * 2);
  __bf16* fcwbf  = (__bf16*)alloc((size_t)NLAY * 4 * NDIM * NDIM * 2);
  __bf16* prjwbf = (__bf16*)alloc((size_t)NLAY * NDIM * 4 * NDIM * 2);
  float* skips[4] = {nullptr, sk1, sk2, sk3};

  cvt_bf16_kernel<<<2048, 256, 0, stream>>>(embed, embbf, (long)NVOC * NDIM);
  cvt_bf16_kernel<<<2048, 256, 0, stream>>>(qkvw, qkvwbf, (long)NLAY * 3 * NHEAD * NHD * NDIM);
  cvt_bf16_kernel<<<2048, 256, 0, stream>>>(aprj, aprjbf, (long)NLAY * NDIM * NDIM);
  cvt_bf16_kernel<<<2048, 256, 0, stream>>>(fcw, fcwbf, (long)NLAY * 4 * NDIM * NDIM);
  cvt_bf16_kernel<<<2048, 256, 0, stream>>>(prjw, prjwbf, (long)NLAY * NDIM * 4 * NDIM);

  prep_kernel<<<1, 1024, 0, stream>>>(seq, wnb, docs, catL, catS);
  embed_rms_kernel<<<NSEQ, 256, 0, stream>>>(seq, embed, x, x0);

  const int velist[NLAY]   = {0, 1, 2, -1, -1, 0, 1, 2};
  const int skipj[NLAY]    = {-1, -1, -1, -1, -1, 3, 2, 1};
  const int maskLong[NLAY] = {1, 0, 0, 0, 1, 0, 0, 1};

  for (int i = 0; i < NLAY; ++i) {
    mix_kernel<<<1024, 256, 0, stream>>>(x, x0, skipj[i] >= 0 ? skips[skipj[i]] : nullptr, scal, i, skipj[i]);
    rmsbf_kernel<<<NSEQ, 256, 0, stream>>>(x, xabf);
    gemm_mfma<0><<<dim3(NSEQ / 128, (3 * NHEAD * NHD) / 128), 256, 0, stream>>>(
        xabf, qkvwbf + (size_t)i * 3 * NHEAD * NHD * NDIM, qkvb, nullptr, 3 * NHEAD * NHD, NDIM);
    qkv_post_kernel<<<NSEQ, 128, 0, stream>>>(qkvb, vemb, seq, scal, i, velist[i], qb, kb, vb);
    attn_kernel<<<dim3(NSEQ / 32, NHEAD), 128, 0, stream>>>(qb, kb, vb, maskLong[i] ? catL : catS, docs, ybf);
    gemm_mfma<1><<<dim3(NSEQ / 128, NDIM / 128), 256, 0, stream>>>(
        ybf, aprjbf + (size_t)i * NDIM * NDIM, x, nullptr, NDIM, NDIM);
    rmsbf_kernel<<<NSEQ, 256, 0, stream>>>(x, xabf);
    gemm_mfma<2><<<dim3(NSEQ / 128, (4 * NDIM) / 128), 256, 0, stream>>>(
        xabf, fcwbf + (size_t)i * 4 * NDIM * NDIM, nullptr, hbf, 4 * NDIM, NDIM);
    gemm_mfma<1><<<dim3(NSEQ / 128, NDIM / 128), 256, 0, stream>>>(
        hbf, prjwbf + (size_t)i * NDIM * 4 * NDIM, x, nullptr, NDIM, 4 * NDIM);
    if (i >= 1 && i <= 3) {
      hipMemcpyAsync(skips[i], x, (size_t)NSEQ * NDIM * 4, hipMemcpyDeviceToDevice, stream);
    }
  }

  rmsbf_kernel<<<NSEQ, 256, 0, stream>>>(x, xbf);
  logits_mfma_kernel<<<dim3(NSEQ / 64, NCHUNK), 256, 0, stream>>>(xbf, embbf, tgt, pm, pl, tc);
  loss_kernel<<<1, 256, 0, stream>>>(pm, pl, tc, out);
}

// Round 4
// 3859.019 us; speedup vs baseline: 2.4796x; 1.1344x over previous
//
#include <hip/hip_runtime.h>
#include <hip/hip_bf16.h>
#include <math.h>

#define NSEQ 2048
#define NDIM 768
#define NLAY 8
#define NHEAD 6
#define NHD 128
#define NVOC 50257
#define NBLK 16
#define BLKSZ 128
#define EOS_TOK 50256
#define EPSF 1.1920929e-07f
#define ASCALE 0.12f
#define VCHUNK 2048
#define NCHUNK 25

using bf16x8 = __attribute__((ext_vector_type(8))) __bf16;
using bf16x4 = __attribute__((ext_vector_type(4))) __bf16;
using f32x4  = __attribute__((ext_vector_type(4))) float;

__device__ __forceinline__ __bf16 tobf(float x) {
  __hip_bfloat16 h = __float2bfloat16(x);
  return *reinterpret_cast<__bf16*>(&h);
}

// ---------------- f32 -> bf16 bulk convert ----------------
__global__ __launch_bounds__(256) void cvt_bf16_kernel(const float* __restrict__ in, __bf16* __restrict__ out,
                                                       long n) {
  long i = ((long)blockIdx.x * blockDim.x + threadIdx.x) * 4;
  long stride = (long)gridDim.x * blockDim.x * 4;
  for (; i < n; i += stride) {
    float4 v = *(const float4*)(in + i);
    bf16x4 o;
    o[0] = tobf(v.x); o[1] = tobf(v.y); o[2] = tobf(v.z); o[3] = tobf(v.w);
    *(bf16x4*)(out + i) = o;
  }
}

// ---------------- prep: docs cumsum + block mask categories ----------------
__global__ __launch_bounds__(1024) void prep_kernel(const int* __restrict__ seq, const int* __restrict__ wptr,
                                                    int* __restrict__ docs, int* __restrict__ catL,
                                                    int* __restrict__ catS) {
  __shared__ int f[NSEQ];
  __shared__ int g[NSEQ];
  int tid = threadIdx.x;
  for (int i = tid; i < NSEQ; i += 1024) f[i] = (seq[i] == EOS_TOK) ? 1 : 0;
  __syncthreads();
  int* a = f; int* b = g;
  for (int off = 1; off < NSEQ; off <<= 1) {
    for (int i = tid; i < NSEQ; i += 1024) {
      int v = a[i];
      if (i >= off) v += a[i - off];
      b[i] = v;
    }
    __syncthreads();
    int* t = a; a = b; b = t;
  }
  for (int i = tid; i < NSEQ; i += 1024) docs[i] = a[i];
  __syncthreads();
  if (tid == 0) {
    int dl[NBLK], dh[NBLK];
    for (int bi = 0; bi < NBLK; ++bi) { dl[bi] = a[bi * BLKSZ]; dh[bi] = a[bi * BLKSZ + BLKSZ - 1]; }
    int W = *wptr;
    for (int pass = 0; pass < 2; ++pass) {
      int w = (pass == 0) ? W : (W / 2);
      int* cat = (pass == 0) ? catL : catS;
      for (int i = 0; i < NBLK; ++i) {
        int allr[NBLK], partr[NBLK];
        int nf = 0, np = 0;
        for (int j = 0; j < NBLK; ++j) {
          int any_ = (i >= j) && (dl[i] <= dh[j]) && (dh[i] >= dl[j]);
          int all_ = (i > j) && (dl[i] == dh[j]) && (dh[i] == dl[j]);
          allr[j] = all_; partr[j] = any_ && !all_;
          nf += all_; np += partr[j];
        }
        int kcf = min(nf, w - 1);
        int kcp = min(np, max(w - nf, 1));
        int cf = 0, cp = 0;
        for (int j = NBLK - 1; j >= 0; --j) {
          int cv = 0;
          if (allr[j]) { cf++; if (cf <= kcf) cv = 2; }
          if (partr[j]) { cp++; if (cp <= kcp) cv = 1; }
          cat[i * NBLK + j] = cv;
        }
      }
    }
  }
}

// ---------------- embedding gather + rms -> x, x0 ----------------
__global__ __launch_bounds__(256) void embed_rms_kernel(const int* __restrict__ seq, const float* __restrict__ embed,
                                                        float* __restrict__ x, float* __restrict__ x0) {
  int s = blockIdx.x;
  int tid = threadIdx.x;
  const float* row = embed + (size_t)seq[s] * NDIM;
  float v0 = row[tid], v1 = row[tid + 256], v2 = row[tid + 512];
  float ss = v0 * v0 + v1 * v1 + v2 * v2;
  __shared__ float red[256];
  red[tid] = ss; __syncthreads();
  for (int o = 128; o > 0; o >>= 1) { if (tid < o) red[tid] += red[tid + o]; __syncthreads(); }
  float sc = rsqrtf(red[0] / (float)NDIM + EPSF);
  size_t base = (size_t)s * NDIM;
  float o0 = v0 * sc, o1 = v1 * sc, o2 = v2 * sc;
  x[base + tid] = o0; x[base + tid + 256] = o1; x[base + tid + 512] = o2;
  x0[base + tid] = o0; x0[base + tid + 256] = o1; x0[base + tid + 512] = o2;
}

// ---------------- row rms -> bf16 ----------------
__global__ __launch_bounds__(256) void rmsbf_kernel(const float* __restrict__ x, __bf16* __restrict__ xb) {
  int s = blockIdx.x;
  int tid = threadIdx.x;
  size_t base = (size_t)s * NDIM;
  float v0 = x[base + tid], v1 = x[base + tid + 256], v2 = x[base + tid + 512];
  float ss = v0 * v0 + v1 * v1 + v2 * v2;
  __shared__ float red[256];
  red[tid] = ss; __syncthreads();
  for (int o = 128; o > 0; o >>= 1) { if (tid < o) red[tid] += red[tid + o]; __syncthreads(); }
  float sc = rsqrtf(red[0] / (float)NDIM + EPSF);
  xb[base + tid] = tobf(v0 * sc); xb[base + tid + 256] = tobf(v1 * sc); xb[base + tid + 512] = tobf(v2 * sc);
}

// ---------------- fused residual mix + rms->bf16 ----------------
// x = lam0*(x + sw*skip) + lam1*x0 ; xb = tobf(rms(x))
__global__ __launch_bounds__(256) void mixrms_kernel(float* __restrict__ x, const float* __restrict__ x0,
                                                     const float* __restrict__ skip, const float* __restrict__ scal,
                                                     int li, int sj, __bf16* __restrict__ xb) {
  float lam0 = scal[NLAY + 2 * li], lam1 = scal[NLAY + 2 * li + 1];
  float sw = (sj >= 0) ? scal[sj] : 0.f;
  int s = blockIdx.x;
  int tid = threadIdx.x;
  size_t base = (size_t)s * NDIM;
  float xv[3], ov[3], nv[3];
  xv[0] = x[base + tid]; xv[1] = x[base + tid + 256]; xv[2] = x[base + tid + 512];
  ov[0] = x0[base + tid]; ov[1] = x0[base + tid + 256]; ov[2] = x0[base + tid + 512];
  if (skip) {
    nv[0] = lam0 * (xv[0] + sw * skip[base + tid])       + lam1 * ov[0];
    nv[1] = lam0 * (xv[1] + sw * skip[base + tid + 256]) + lam1 * ov[1];
    nv[2] = lam0 * (xv[2] + sw * skip[base + tid + 512]) + lam1 * ov[2];
  } else {
    nv[0] = lam0 * xv[0] + lam1 * ov[0];
    nv[1] = lam0 * xv[1] + lam1 * ov[1];
    nv[2] = lam0 * xv[2] + lam1 * ov[2];
  }
  x[base + tid] = nv[0]; x[base + tid + 256] = nv[1]; x[base + tid + 512] = nv[2];
  float ss = nv[0] * nv[0] + nv[1] * nv[1] + nv[2] * nv[2];
  __shared__ float red[256];
  red[tid] = ss; __syncthreads();
  for (int o = 128; o > 0; o >>= 1) { if (tid < o) red[tid] += red[tid + o]; __syncthreads(); }
  float sc = rsqrtf(red[0] / (float)NDIM + EPSF);
  xb[base + tid] = tobf(nv[0] * sc); xb[base + tid + 256] = tobf(nv[1] * sc); xb[base + tid + 512] = tobf(nv[2] * sc);
}

// ---------------- bf16 MFMA GEMM 128x128: C[m][n] = sum_k A[m][k]*B[n][k] ----------------
// MODE 0: store f32; 1: accumulate into f32; 2: relu(acc)^2 -> bf16
template <int MODE>
__global__ __launch_bounds__(256) void gemm_mfma(const __bf16* __restrict__ A, const __bf16* __restrict__ B,
                                                 float* __restrict__ Cf, __bf16* __restrict__ Cb,
                                                 int N, int K) {
  __shared__ __bf16 As[128][40];
  __shared__ __bf16 Bs[128][40];
  int bm = blockIdx.x * 128, bn = blockIdx.y * 128;
  int tid = threadIdx.x;
  int w = tid >> 6, l = tid & 63;
  int wm = (w >> 1) * 64, wn = (w & 1) * 64;
  int c = l & 15, g = l >> 4;
  int srow = tid >> 1, shalf = (tid & 1) * 16;
  const __bf16* Ap = A + (size_t)(bm + srow) * K + shalf;
  const __bf16* Bp = B + (size_t)(bn + srow) * K + shalf;
  f32x4 acc[4][4] = {};
  for (int k0 = 0; k0 < K; k0 += 32) {
    bf16x8 av0 = *(const bf16x8*)(Ap + k0);
    bf16x8 av1 = *(const bf16x8*)(Ap + k0 + 8);
    bf16x8 bv0 = *(const bf16x8*)(Bp + k0);
    bf16x8 bv1 = *(const bf16x8*)(Bp + k0 + 8);
    __syncthreads();
    *(bf16x8*)&As[srow][shalf] = av0; *(bf16x8*)&As[srow][shalf + 8] = av1;
    *(bf16x8*)&Bs[srow][shalf] = bv0; *(bf16x8*)&Bs[srow][shalf + 8] = bv1;
    __syncthreads();
    bf16x8 af[4], bfr[4];
#pragma unroll
    for (int i = 0; i < 4; ++i) af[i] = *(const bf16x8*)&As[wm + i * 16 + c][g * 8];
#pragma unroll
    for (int j = 0; j < 4; ++j) bfr[j] = *(const bf16x8*)&Bs[wn + j * 16 + c][g * 8];
#pragma unroll
    for (int i = 0; i < 4; ++i)
#pragma unroll
      for (int j = 0; j < 4; ++j)
        acc[i][j] = __builtin_amdgcn_mfma_f32_16x16x32_bf16(af[i], bfr[j], acc[i][j], 0, 0, 0);
  }
#pragma unroll
  for (int i = 0; i < 4; ++i)
#pragma unroll
    for (int j = 0; j < 4; ++j)
#pragma unroll
      for (int rr = 0; rr < 4; ++rr) {
        int row = bm + wm + i * 16 + g * 4 + rr;
        int col = bn + wn + j * 16 + c;
        size_t ci = (size_t)row * N + col;
        float z = acc[i][j][rr];
        if (MODE == 0) Cf[ci] = z;
        else if (MODE == 1) Cf[ci] += z;
        else { float r = fmaxf(z, 0.f); Cb[ci] = tobf(r * r); }
      }
}

// ---------------- bf16 MFMA GEMM 64x64 (for N=768 projections) ----------------
template <int MODE>
__global__ __launch_bounds__(256) void gemm_mfma64(const __bf16* __restrict__ A, const __bf16* __restrict__ B,
                                                   float* __restrict__ Cf, __bf16* __restrict__ Cb,
                                                   int N, int K) {
  __shared__ __bf16 As[64][40];
  __shared__ __bf16 Bs[64][40];
  int bm = blockIdx.x * 64, bn = blockIdx.y * 64;
  int tid = threadIdx.x;
  int w = tid >> 6, l = tid & 63;
  int wm = (w >> 1) * 32, wn = (w & 1) * 32;
  int c = l & 15, g = l >> 4;
  int srow = tid >> 2, scol = (tid & 3) * 8;
  const __bf16* Ap = A + (size_t)(bm + srow) * K + scol;
  const __bf16* Bp = B + (size_t)(bn + srow) * K + scol;
  f32x4 acc[2][2] = {};
  for (int k0 = 0; k0 < K; k0 += 32) {
    bf16x8 av = *(const bf16x8*)(Ap + k0);
    bf16x8 bv = *(const bf16x8*)(Bp + k0);
    __syncthreads();
    *(bf16x8*)&As[srow][scol] = av;
    *(bf16x8*)&Bs[srow][scol] = bv;
    __syncthreads();
    bf16x8 af[2], bfr[2];
#pragma unroll
    for (int i = 0; i < 2; ++i) af[i] = *(const bf16x8*)&As[wm + i * 16 + c][g * 8];
#pragma unroll
    for (int j = 0; j < 2; ++j) bfr[j] = *(const bf16x8*)&Bs[wn + j * 16 + c][g * 8];
#pragma unroll
    for (int i = 0; i < 2; ++i)
#pragma unroll
      for (int j = 0; j < 2; ++j)
        acc[i][j] = __builtin_amdgcn_mfma_f32_16x16x32_bf16(af[i], bfr[j], acc[i][j], 0, 0, 0);
  }
#pragma unroll
  for (int i = 0; i < 2; ++i)
#pragma unroll
    for (int j = 0; j < 2; ++j)
#pragma unroll
      for (int rr = 0; rr < 4; ++rr) {
        int row = bm + wm + i * 16 + g * 4 + rr;
        int col = bn + wn + j * 16 + c;
        size_t ci = (size_t)row * N + col;
        float z = acc[i][j][rr];
        if (MODE == 0) Cf[ci] = z;
        else if (MODE == 1) Cf[ci] += z;
        else { float r = fmaxf(z, 0.f); Cb[ci] = tobf(r * r); }
      }
}

// ---------------- qkv post: wave per (s,h); lane l owns dims l and l+64 ----------------
__global__ __launch_bounds__(256) void qkv_post_kernel(const float* __restrict__ qkv, const float* __restrict__ vemb,
                                                       const int* __restrict__ seq, const float* __restrict__ scal,
                                                       int li, int ve_idx,
                                                       float* __restrict__ qo, float* __restrict__ ko,
                                                       float* __restrict__ vo) {
  int p = blockIdx.x * 4 + (threadIdx.x >> 6);  // p = h*NSEQ + s
  int l = threadIdx.x & 63;
  int h = p >> 11;          // / NSEQ
  int s = p & (NSEQ - 1);
  float sal0 = scal[3 * NLAY + 2 * li], sal1 = scal[3 * NLAY + 2 * li + 1];
  float fr = (l < 32) ? powf(1.0f / 1024.0f, (float)l * (1.0f / 31.0f)) : 0.f;
  float th = (float)s * fr;
  float cth = cosf(th), sth = sinf(th);
  size_t rb = (size_t)s * (3 * NHEAD * NHD) + h * NHD;
  float q0 = qkv[rb + l],                 q1 = qkv[rb + l + 64];
  float k0 = qkv[rb + NHEAD * NHD + l],   k1 = qkv[rb + NHEAD * NHD + l + 64];
  float v0 = qkv[rb + 2 * NHEAD * NHD + l], v1 = qkv[rb + 2 * NHEAD * NHD + l + 64];
  float ssq = q0 * q0 + q1 * q1;
  float ssk = k0 * k0 + k1 * k1;
#pragma unroll
  for (int o = 1; o < 64; o <<= 1) {
    ssq += __shfl_xor(ssq, o, 64);
    ssk += __shfl_xor(ssk, o, 64);
  }
  float scq = rsqrtf(ssq / (float)NHD + EPSF);
  float sck = rsqrtf(ssk / (float)NHD + EPSF);
  float qn0 = q0 * scq, qn1 = q1 * scq;
  float kn0 = k0 * sck, kn1 = k1 * sck;
  float oq0 = qn0 * cth + qn1 * sth, oq1 = -qn0 * sth + qn1 * cth;
  float ok0 = kn0 * cth + kn1 * sth, ok1 = -kn0 * sth + kn1 * cth;
  float ov0 = sal0 * v0, ov1 = sal0 * v1;
  if (ve_idx >= 0) {
    const float* ver = vemb + ((size_t)ve_idx * NVOC + seq[s]) * NDIM + h * NHD;
    ov0 += sal1 * ver[l];
    ov1 += sal1 * ver[l + 64];
  }
  size_t oo = ((size_t)h * NSEQ + s) * NHD;
  qo[oo + l] = oq0; qo[oo + l + 64] = oq1;
  ko[oo + l] = ok0; ko[oo + l + 64] = ok1;
  vo[oo + l] = ov0; vo[oo + l + 64] = ov1;
}

// ---------------- flash attention, 8 lanes per q-row, 256 threads ----------------
__global__ __launch_bounds__(256) void attn_kernel(const float* __restrict__ q, const float* __restrict__ k,
                                                   const float* __restrict__ v, const int* __restrict__ cat,
                                                   const int* __restrict__ docs, __bf16* __restrict__ y) {
  int qb = blockIdx.x;
  int h = blockIdx.y;
  int tid = threadIdx.x;
  int r = tid >> 3;       // 0..31 q-row within block
  int qt = tid & 7;       // 8 lanes per row, 16 dims each
  int rg = qb * 32 + r;
  int qB = qb >> 2;
  __shared__ float Ks[32][NHD];
  __shared__ float Vs[32][NHD];
  __shared__ int kd[32];
  const float4* qp = (const float4*)(q + ((size_t)h * NSEQ + rg) * NHD + qt * 16);
  float4 qv[4];
#pragma unroll
  for (int i = 0; i < 4; ++i) qv[i] = qp[i];
  float acc[16];
#pragma unroll
  for (int i = 0; i < 16; ++i) acc[i] = 0.f;
  float mrun = -INFINITY, lrun = 0.f;
  int mydoc = docs[rg];
  int nkb = (qB + 1) * (BLKSZ / 32);
  for (int kb = 0; kb < nkb; ++kb) {
    int c = cat[qB * NBLK + (kb >> 2)];
    if (c == 0) continue;
    __syncthreads();
    {
      const float4* ksrc = (const float4*)(k + ((size_t)h * NSEQ + kb * 32) * NHD);
      const float4* vsrc = (const float4*)(v + ((size_t)h * NSEQ + kb * 32) * NHD);
      float4* kdst = (float4*)&Ks[0][0];
      float4* vdst = (float4*)&Vs[0][0];
      for (int i = tid; i < 32 * NHD / 4; i += 256) { kdst[i] = ksrc[i]; vdst[i] = vsrc[i]; }
      if (tid < 32) kd[tid] = docs[kb * 32 + tid];
    }
    __syncthreads();
    float sc[32];
#pragma unroll
    for (int kk = 0; kk < 32; ++kk) {
      const float4* kp = (const float4*)&Ks[kk][qt * 16];
      float sa = 0.f;
#pragma unroll
      for (int i = 0; i < 4; ++i) {
        float4 aa = qv[i], bb = kp[i];
        sa += aa.x * bb.x + aa.y * bb.y + aa.z * bb.z + aa.w * bb.w;
      }
      sa += __shfl_xor(sa, 1, 64);
      sa += __shfl_xor(sa, 2, 64);
      sa += __shfl_xor(sa, 4, 64);
      int kg = kb * 32 + kk;
      bool okm = (c == 2) || ((kg <= rg) && (kd[kk] == mydoc));
      sc[kk] = okm ? sa * ASCALE : -INFINITY;
    }
    float bmx = sc[0];
#pragma unroll
    for (int kk = 1; kk < 32; ++kk) bmx = fmaxf(bmx, sc[kk]);
    float mnew = fmaxf(mrun, bmx);
    if (mnew == -INFINITY) continue;
    float corr = __expf(mrun - mnew);
    lrun *= corr;
#pragma unroll
    for (int i = 0; i < 16; ++i) acc[i] *= corr;
#pragma unroll
    for (int kk = 0; kk < 32; ++kk) {
      float p = __expf(sc[kk] - mnew);
      lrun += p;
      const float* vp = &Vs[kk][qt * 16];
#pragma unroll
      for (int i = 0; i < 16; ++i) acc[i] += p * vp[i];
    }
    mrun = mnew;
  }
  float inv = 1.f / lrun;
  __bf16* yo = y + (size_t)rg * (NHEAD * NHD) + h * NHD + qt * 16;
#pragma unroll
  for (int i = 0; i < 16; ++i) yo[i] = tobf(acc[i] * inv);
}

// ---------------- MFMA logits, 128-wide vocab tiles, XOR-swizzled LDS ----------------
#define LSTRIDE 272  // bytes per LDS row (136 bf16)
#define SWZ(row, cb) ((cb) ^ (((row) & 7) << 4))
__global__ __launch_bounds__(256) void logits_mfma_kernel(const __bf16* __restrict__ xbf,
                                                          const __bf16* __restrict__ embed_bf,
                                                          const int* __restrict__ target,
                                                          float* __restrict__ part_m, float* __restrict__ part_l,
                                                          float* __restrict__ tcap) {
  int tb = blockIdx.x;
  int ch = blockIdx.y;
  int tid = threadIdx.x;
  int w = tid >> 6;
  int l = tid & 63;
  int c = l & 15;
  int g = l >> 4;

  __shared__ char Bs[128 * LSTRIDE];

  const __bf16* xrow = xbf + (size_t)(tb * 64 + w * 16 + c) * NDIM + g * 8;
  bf16x8 afrag[24];
#pragma unroll
  for (int kc = 0; kc < 24; ++kc) afrag[kc] = *(const bf16x8*)(xrow + kc * 32);

  int tgv[4];
#pragma unroll
  for (int rr = 0; rr < 4; ++rr) tgv[rr] = target[tb * 64 + w * 16 + g * 4 + rr];

  float rowm[4], rowl[4];
#pragma unroll
  for (int rr = 0; rr < 4; ++rr) { rowm[rr] = -INFINITY; rowl[rr] = 0.f; }

  int srow = tid >> 1;            // staging row 0..127
  int shalf = (tid & 1) * 64;     // col half (elements)

  for (int vt = 0; vt < VCHUNK / 128; ++vt) {
    int vb0 = ch * VCHUNK + vt * 128;
    if (vb0 >= NVOC) break;
    f32x4 acc[8] = {};
#pragma unroll
    for (int kc = 0; kc < 6; ++kc) {
      __syncthreads();
      {
        int vrow = vb0 + srow;
        bool okr = vrow < NVOC;
        const __bf16* src = embed_bf + (size_t)vrow * NDIM + kc * 128 + shalf;
        bf16x8 zv = {};
#pragma unroll
        for (int i = 0; i < 8; ++i) {
          bf16x8 bv = okr ? *(const bf16x8*)(src + i * 8) : zv;
          int cb = (shalf + i * 8) * 2;
          *(bf16x8*)(Bs + srow * LSTRIDE + SWZ(srow, cb)) = bv;
        }
      }
      __syncthreads();
#pragma unroll
      for (int ks = 0; ks < 4; ++ks) {
#pragma unroll
        for (int nt = 0; nt < 8; ++nt) {
          int row = nt * 16 + c;
          int cb = (ks * 32 + g * 8) * 2;
          bf16x8 bfr = *(const bf16x8*)(Bs + row * LSTRIDE + SWZ(row, cb));
          acc[nt] = __builtin_amdgcn_mfma_f32_16x16x32_bf16(afrag[kc * 4 + ks], bfr, acc[nt], 0, 0, 0);
        }
      }
    }
    // epilogue: soft-cap (recomputed in 2nd pass to save VGPR), target grab, online (max,sum)
    float tmax[4];
#pragma unroll
    for (int rr = 0; rr < 4; ++rr) tmax[rr] = -INFINITY;
#pragma unroll
    for (int nt = 0; nt < 8; ++nt) {
      int vv = vb0 + nt * 16 + c;
      bool okv = vv < NVOC;
#pragma unroll
      for (int rr = 0; rr < 4; ++rr) {
        float z = acc[nt][rr];
        float cp = okv ? 15.f * z * rsqrtf(z * z + 225.f) : -INFINITY;
        tmax[rr] = fmaxf(tmax[rr], cp);
        if (okv && vv == tgv[rr]) tcap[tb * 64 + w * 16 + g * 4 + rr] = cp;
      }
    }
#pragma unroll
    for (int rr = 0; rr < 4; ++rr) {
      tmax[rr] = fmaxf(tmax[rr], __shfl_xor(tmax[rr], 1, 64));
      tmax[rr] = fmaxf(tmax[rr], __shfl_xor(tmax[rr], 2, 64));
      tmax[rr] = fmaxf(tmax[rr], __shfl_xor(tmax[rr], 4, 64));
      tmax[rr] = fmaxf(tmax[rr], __shfl_xor(tmax[rr], 8, 64));
    }
    float tsum[4] = {0.f, 0.f, 0.f, 0.f};
#pragma unroll
    for (int nt = 0; nt < 8; ++nt) {
      int vv = vb0 + nt * 16 + c;
      bool okv = vv < NVOC;
#pragma unroll
      for (int rr = 0; rr < 4; ++rr) {
        float z = acc[nt][rr];
        float cp = okv ? 15.f * z * rsqrtf(z * z + 225.f) : -INFINITY;
        tsum[rr] += __expf(cp - tmax[rr]);
      }
    }
#pragma unroll
    for (int rr = 0; rr < 4; ++rr) {
      tsum[rr] += __shfl_xor(tsum[rr], 1, 64);
      tsum[rr] += __shfl_xor(tsum[rr], 2, 64);
      tsum[rr] += __shfl_xor(tsum[rr], 4, 64);
      tsum[rr] += __shfl_xor(tsum[rr], 8, 64);
    }
#pragma unroll
    for (int rr = 0; rr < 4; ++rr) {
      float mn = fmaxf(rowm[rr], tmax[rr]);
      rowl[rr] = rowl[rr] * __expf(rowm[rr] - mn) + tsum[rr] * __expf(tmax[rr] - mn);
      rowm[rr] = mn;
    }
  }
  if (c == 0) {
#pragma unroll
    for (int rr = 0; rr < 4; ++rr) {
      int row = tb * 64 + w * 16 + g * 4 + rr;
      part_m[(size_t)ch * NSEQ + row] = rowm[rr];
      part_l[(size_t)ch * NSEQ + row] = rowl[rr];
    }
  }
}

// ---------------- final loss reduce ----------------
__global__ __launch_bounds__(256) void loss_kernel(const float* __restrict__ part_m, const float* __restrict__ part_l,
                                                   const float* __restrict__ tcap, float* __restrict__ out) {
  int tid = threadIdx.x;
  float sum = 0.f;
  for (int t = tid; t < NSEQ; t += 256) {
    float M = -INFINITY;
    for (int cc = 0; cc < NCHUNK; ++cc) M = fmaxf(M, part_m[(size_t)cc * NSEQ + t]);
    float Lq = 0.f;
    for (int cc = 0; cc < NCHUNK; ++cc) Lq += part_l[(size_t)cc * NSEQ + t] * __expf(part_m[(size_t)cc * NSEQ + t] - M);
    sum += (M + logf(Lq)) - tcap[t];
  }
  __shared__ float red[256];
  red[tid] = sum; __syncthreads();
  for (int o = 128; o > 0; o >>= 1) { if (tid < o) red[tid] += red[tid + o]; __syncthreads(); }
  if (tid == 0) out[0] = red[0] / (float)NSEQ;
}

// ---------------- host driver ----------------
extern "C" void kernel_launch(void* const* d_in, const int* in_sizes, int n_in,
                              void* d_out, int out_size, void* d_ws, size_t ws_size,
                              hipStream_t stream) {
  const int* seq   = (const int*)d_in[0];
  const int* wnb   = (const int*)d_in[1];
  const int* tgt   = (const int*)d_in[2];
  const float* embed = (const float*)d_in[3];
  const float* vemb  = (const float*)d_in[4];
  const float* qkvw  = (const float*)d_in[5];
  const float* aprj  = (const float*)d_in[6];
  const float* fcw   = (const float*)d_in[7];
  const float* prjw  = (const float*)d_in[8];
  const float* scal  = (const float*)d_in[9];
  float* out = (float*)d_out;

  char* w = (char*)d_ws;
  auto alloc = [&](size_t bytes) {
    char* p = w;
    w += (bytes + 255) & ~(size_t)255;
    return p;
  };
  int* docs = (int*)alloc(NSEQ * 4);
  int* catL = (int*)alloc(NBLK * NBLK * 4);
  int* catS = (int*)alloc(NBLK * NBLK * 4);
  float* x    = (float*)alloc((size_t)NSEQ * NDIM * 4);
  float* x0   = (float*)alloc((size_t)NSEQ * NDIM * 4);
  float* sk1  = (float*)alloc((size_t)NSEQ * NDIM * 4);
  float* sk2  = (float*)alloc((size_t)NSEQ * NDIM * 4);
  float* sk3  = (float*)alloc((size_t)NSEQ * NDIM * 4);
  float* qkvb = (float*)alloc((size_t)NSEQ * 3 * NHEAD * NHD * 4);
  float* qb   = (float*)alloc((size_t)NHEAD * NSEQ * NHD * 4);
  float* kb   = (float*)alloc((size_t)NHEAD * NSEQ * NHD * 4);
  float* vb   = (float*)alloc((size_t)NHEAD * NSEQ * NHD * 4);
  __bf16* xabf = (__bf16*)alloc((size_t)NSEQ * NDIM * 2);
  __bf16* ybf  = (__bf16*)alloc((size_t)NSEQ * NDIM * 2);
  __bf16* hbf  = (__bf16*)alloc((size_t)NSEQ * 4 * NDIM * 2);
  __bf16* xbf  = (__bf16*)alloc((size_t)NSEQ * NDIM * 2);
  float* pm   = (float*)alloc((size_t)NCHUNK * NSEQ * 4);
  float* pl   = (float*)alloc((size_t)NCHUNK * NSEQ * 4);
  float* tc   = (float*)alloc((size_t)NSEQ * 4);
  __bf16* embbf = (__bf16*)alloc((size_t)NVOC * NDIM * 2);
  __bf16* qkvwbf = (__bf16*)alloc((size_t)NLAY * 3 * NHEAD * NHD * NDIM * 2);
  __bf16* aprjbf = (__bf16*)alloc((size_t)NLAY * NDIM * NDIM * 2);
  __bf16* fcwbf  = (__bf16*)alloc((size_t)NLAY * 4 * NDIM * NDIM * 2);
  __bf16* prjwbf = (__bf16*)alloc((size_t)NLAY * NDIM * 4 * NDIM * 2);
  float* skips[4] = {nullptr, sk1, sk2, sk3};

  cvt_bf16_kernel<<<2048, 256, 0, stream>>>(embed, embbf, (long)NVOC * NDIM);
  cvt_bf16_kernel<<<2048, 256, 0, stream>>>(qkvw, qkvwbf, (long)NLAY * 3 * NHEAD * NHD * NDIM);
  cvt_bf16_kernel<<<2048, 256, 0, stream>>>(aprj, aprjbf, (long)NLAY * NDIM * NDIM);
  cvt_bf16_kernel<<<2048, 256, 0, stream>>>(fcw, fcwbf, (long)NLAY * 4 * NDIM * NDIM);
  cvt_bf16_kernel<<<2048, 256, 0, stream>>>(prjw, prjwbf, (long)NLAY * NDIM * 4 * NDIM);

  prep_kernel<<<1, 1024, 0, stream>>>(seq, wnb, docs, catL, catS);
  embed_rms_kernel<<<NSEQ, 256, 0, stream>>>(seq, embed, x, x0);

  const int velist[NLAY]   = {0, 1, 2, -1, -1, 0, 1, 2};
  const int skipj[NLAY]    = {-1, -1, -1, -1, -1, 3, 2, 1};
  const int maskLong[NLAY] = {1, 0, 0, 0, 1, 0, 0, 1};

  for (int i = 0; i < NLAY; ++i) {
    mixrms_kernel<<<NSEQ, 256, 0, stream>>>(x, x0, skipj[i] >= 0 ? skips[skipj[i]] : nullptr, scal, i, skipj[i], xabf);
    gemm_mfma<0><<<dim3(NSEQ / 128, (3 * NHEAD * NHD) / 128), 256, 0, stream>>>(
        xabf, qkvwbf + (size_t)i * 3 * NHEAD * NHD * NDIM, qkvb, nullptr, 3 * NHEAD * NHD, NDIM);
    qkv_post_kernel<<<NHEAD * NSEQ / 4, 256, 0, stream>>>(qkvb, vemb, seq, scal, i, velist[i], qb, kb, vb);
    attn_kernel<<<dim3(NSEQ / 32, NHEAD), 256, 0, stream>>>(qb, kb, vb, maskLong[i] ? catL : catS, docs, ybf);
    gemm_mfma64<1><<<dim3(NSEQ / 64, NDIM / 64), 256, 0, stream>>>(
        ybf, aprjbf + (size_t)i * NDIM * NDIM, x, nullptr, NDIM, NDIM);
    rmsbf_kernel<<<NSEQ, 256, 0, stream>>>(x, xabf);
    gemm_mfma<2><<<dim3(NSEQ / 128, (4 * NDIM) / 128), 256, 0, stream>>>(
        xabf, fcwbf + (size_t)i * 4 * NDIM * NDIM, nullptr, hbf, 4 * NDIM, NDIM);
    gemm_mfma64<1><<<dim3(NSEQ / 64, NDIM / 64), 256, 0, stream>>>(
        hbf, prjwbf + (size_t)i * NDIM * 4 * NDIM, x, nullptr, NDIM, 4 * NDIM);
    if (i >= 1 && i <= 3) {
      hipMemcpyAsync(skips[i], x, (size_t)NSEQ * NDIM * 4, hipMemcpyDeviceToDevice, stream);
    }
  }

  rmsbf_kernel<<<NSEQ, 256, 0, stream>>>(x, xbf);
  logits_mfma_kernel<<<dim3(NSEQ / 64, NCHUNK), 256, 0, stream>>>(xbf, embbf, tgt, pm, pl, tc);
  loss_kernel<<<1, 256, 0, stream>>>(pm, pl, tc, out);
}

// Round 6
// 3440.638 us; speedup vs baseline: 2.7811x; 1.1216x over previous
//
#include <hip/hip_runtime.h>
#include <hip/hip_bf16.h>
#include <math.h>

#define NSEQ 2048
#define NDIM 768
#define NLAY 8
#define NHEAD 6
#define NHD 128
#define NVOC 50257
#define NBLK 16
#define BLKSZ 128
#define EOS_TOK 50256
#define EPSF 1.1920929e-07f
#define ASCALE 0.12f
#define VCHUNK 1024
#define NCHUNK 50
#define VTW 128
#define KCH 128

using bf16x8 = __attribute__((ext_vector_type(8))) __bf16;
using bf16x4 = __attribute__((ext_vector_type(4))) __bf16;
using f32x4  = __attribute__((ext_vector_type(4))) float;

__device__ __forceinline__ __bf16 tobf(float x) {
  __hip_bfloat16 h = __float2bfloat16(x);
  return *reinterpret_cast<__bf16*>(&h);
}

// ---------------- f32 -> bf16 bulk convert ----------------
__global__ __launch_bounds__(256) void cvt_bf16_kernel(const float* __restrict__ in, __bf16* __restrict__ out,
                                                       long n) {
  long i = ((long)blockIdx.x * blockDim.x + threadIdx.x) * 4;
  long stride = (long)gridDim.x * blockDim.x * 4;
  for (; i < n; i += stride) {
    float4 v = *(const float4*)(in + i);
    bf16x4 o;
    o[0] = tobf(v.x); o[1] = tobf(v.y); o[2] = tobf(v.z); o[3] = tobf(v.w);
    *(bf16x4*)(out + i) = o;
  }
}

// ---------------- prep: docs cumsum + block mask categories ----------------
__global__ __launch_bounds__(1024) void prep_kernel(const int* __restrict__ seq, const int* __restrict__ wptr,
                                                    int* __restrict__ docs, int* __restrict__ catL,
                                                    int* __restrict__ catS) {
  __shared__ int f[NSEQ];
  __shared__ int g[NSEQ];
  int tid = threadIdx.x;
  for (int i = tid; i < NSEQ; i += 1024) f[i] = (seq[i] == EOS_TOK) ? 1 : 0;
  __syncthreads();
  int* a = f; int* b = g;
  for (int off = 1; off < NSEQ; off <<= 1) {
    for (int i = tid; i < NSEQ; i += 1024) {
      int v = a[i];
      if (i >= off) v += a[i - off];
      b[i] = v;
    }
    __syncthreads();
    int* t = a; a = b; b = t;
  }
  for (int i = tid; i < NSEQ; i += 1024) docs[i] = a[i];
  __syncthreads();
  if (tid == 0) {
    int dl[NBLK], dh[NBLK];
    for (int bi = 0; bi < NBLK; ++bi) { dl[bi] = a[bi * BLKSZ]; dh[bi] = a[bi * BLKSZ + BLKSZ - 1]; }
    int W = *wptr;
    for (int pass = 0; pass < 2; ++pass) {
      int w = (pass == 0) ? W : (W / 2);
      int* cat = (pass == 0) ? catL : catS;
      for (int i = 0; i < NBLK; ++i) {
        int allr[NBLK], partr[NBLK];
        int nf = 0, np = 0;
        for (int j = 0; j < NBLK; ++j) {
          int any_ = (i >= j) && (dl[i] <= dh[j]) && (dh[i] >= dl[j]);
          int all_ = (i > j) && (dl[i] == dh[j]) && (dh[i] == dl[j]);
          allr[j] = all_; partr[j] = any_ && !all_;
          nf += all_; np += partr[j];
        }
        int kcf = min(nf, w - 1);
        int kcp = min(np, max(w - nf, 1));
        int cf = 0, cp = 0;
        for (int j = NBLK - 1; j >= 0; --j) {
          int cv = 0;
          if (allr[j]) { cf++; if (cf <= kcf) cv = 2; }
          if (partr[j]) { cp++; if (cp <= kcp) cv = 1; }
          cat[i * NBLK + j] = cv;
        }
      }
    }
  }
}

// ---------------- embedding gather + rms -> x, x0 ----------------
__global__ __launch_bounds__(256) void embed_rms_kernel(const int* __restrict__ seq, const float* __restrict__ embed,
                                                        float* __restrict__ x, float* __restrict__ x0) {
  int s = blockIdx.x;
  int tid = threadIdx.x;
  const float* row = embed + (size_t)seq[s] * NDIM;
  float v0 = row[tid], v1 = row[tid + 256], v2 = row[tid + 512];
  float ss = v0 * v0 + v1 * v1 + v2 * v2;
  __shared__ float red[256];
  red[tid] = ss; __syncthreads();
  for (int o = 128; o > 0; o >>= 1) { if (tid < o) red[tid] += red[tid + o]; __syncthreads(); }
  float sc = rsqrtf(red[0] / (float)NDIM + EPSF);
  size_t base = (size_t)s * NDIM;
  float o0 = v0 * sc, o1 = v1 * sc, o2 = v2 * sc;
  x[base + tid] = o0; x[base + tid + 256] = o1; x[base + tid + 512] = o2;
  x0[base + tid] = o0; x0[base + tid + 256] = o1; x0[base + tid + 512] = o2;
}

// ---------------- row rms -> bf16 ----------------
__global__ __launch_bounds__(256) void rmsbf_kernel(const float* __restrict__ x, __bf16* __restrict__ xb) {
  int s = blockIdx.x;
  int tid = threadIdx.x;
  size_t base = (size_t)s * NDIM;
  float v0 = x[base + tid], v1 = x[base + tid + 256], v2 = x[base + tid + 512];
  float ss = v0 * v0 + v1 * v1 + v2 * v2;
  __shared__ float red[256];
  red[tid] = ss; __syncthreads();
  for (int o = 128; o > 0; o >>= 1) { if (tid < o) red[tid] += red[tid + o]; __syncthreads(); }
  float sc = rsqrtf(red[0] / (float)NDIM + EPSF);
  xb[base + tid] = tobf(v0 * sc); xb[base + tid + 256] = tobf(v1 * sc); xb[base + tid + 512] = tobf(v2 * sc);
}

// ---------------- fused residual mix + rms->bf16 ----------------
__global__ __launch_bounds__(256) void mixrms_kernel(float* __restrict__ x, const float* __restrict__ x0,
                                                     const float* __restrict__ skip, const float* __restrict__ scal,
                                                     int li, int sj, __bf16* __restrict__ xb) {
  float lam0 = scal[NLAY + 2 * li], lam1 = scal[NLAY + 2 * li + 1];
  float sw = (sj >= 0) ? scal[sj] : 0.f;
  int s = blockIdx.x;
  int tid = threadIdx.x;
  size_t base = (size_t)s * NDIM;
  float xv[3], ov[3], nv[3];
  xv[0] = x[base + tid]; xv[1] = x[base + tid + 256]; xv[2] = x[base + tid + 512];
  ov[0] = x0[base + tid]; ov[1] = x0[base + tid + 256]; ov[2] = x0[base + tid + 512];
  if (skip) {
    nv[0] = lam0 * (xv[0] + sw * skip[base + tid])       + lam1 * ov[0];
    nv[1] = lam0 * (xv[1] + sw * skip[base + tid + 256]) + lam1 * ov[1];
    nv[2] = lam0 * (xv[2] + sw * skip[base + tid + 512]) + lam1 * ov[2];
  } else {
    nv[0] = lam0 * xv[0] + lam1 * ov[0];
    nv[1] = lam0 * xv[1] + lam1 * ov[1];
    nv[2] = lam0 * xv[2] + lam1 * ov[2];
  }
  x[base + tid] = nv[0]; x[base + tid + 256] = nv[1]; x[base + tid + 512] = nv[2];
  float ss = nv[0] * nv[0] + nv[1] * nv[1] + nv[2] * nv[2];
  __shared__ float red[256];
  red[tid] = ss; __syncthreads();
  for (int o = 128; o > 0; o >>= 1) { if (tid < o) red[tid] += red[tid + o]; __syncthreads(); }
  float sc = rsqrtf(red[0] / (float)NDIM + EPSF);
  xb[base + tid] = tobf(nv[0] * sc); xb[base + tid + 256] = tobf(nv[1] * sc); xb[base + tid + 512] = tobf(nv[2] * sc);
}

// ---------------- bf16 MFMA GEMM 128x128 ----------------
template <int MODE>
__global__ __launch_bounds__(256) void gemm_mfma(const __bf16* __restrict__ A, const __bf16* __restrict__ B,
                                                 float* __restrict__ Cf, __bf16* __restrict__ Cb,
                                                 int N, int K) {
  __shared__ __bf16 As[128][40];
  __shared__ __bf16 Bs[128][40];
  int bm = blockIdx.x * 128, bn = blockIdx.y * 128;
  int tid = threadIdx.x;
  int w = tid >> 6, l = tid & 63;
  int wm = (w >> 1) * 64, wn = (w & 1) * 64;
  int c = l & 15, g = l >> 4;
  int srow = tid >> 1, shalf = (tid & 1) * 16;
  const __bf16* Ap = A + (size_t)(bm + srow) * K + shalf;
  const __bf16* Bp = B + (size_t)(bn + srow) * K + shalf;
  f32x4 acc[4][4] = {};
  for (int k0 = 0; k0 < K; k0 += 32) {
    bf16x8 av0 = *(const bf16x8*)(Ap + k0);
    bf16x8 av1 = *(const bf16x8*)(Ap + k0 + 8);
    bf16x8 bv0 = *(const bf16x8*)(Bp + k0);
    bf16x8 bv1 = *(const bf16x8*)(Bp + k0 + 8);
    __syncthreads();
    *(bf16x8*)&As[srow][shalf] = av0; *(bf16x8*)&As[srow][shalf + 8] = av1;
    *(bf16x8*)&Bs[srow][shalf] = bv0; *(bf16x8*)&Bs[srow][shalf + 8] = bv1;
    __syncthreads();
    bf16x8 af[4], bfr[4];
#pragma unroll
    for (int i = 0; i < 4; ++i) af[i] = *(const bf16x8*)&As[wm + i * 16 + c][g * 8];
#pragma unroll
    for (int j = 0; j < 4; ++j) bfr[j] = *(const bf16x8*)&Bs[wn + j * 16 + c][g * 8];
#pragma unroll
    for (int i = 0; i < 4; ++i)
#pragma unroll
      for (int j = 0; j < 4; ++j)
        acc[i][j] = __builtin_amdgcn_mfma_f32_16x16x32_bf16(af[i], bfr[j], acc[i][j], 0, 0, 0);
  }
#pragma unroll
  for (int i = 0; i < 4; ++i)
#pragma unroll
    for (int j = 0; j < 4; ++j)
#pragma unroll
      for (int rr = 0; rr < 4; ++rr) {
        int row = bm + wm + i * 16 + g * 4 + rr;
        int col = bn + wn + j * 16 + c;
        size_t ci = (size_t)row * N + col;
        float z = acc[i][j][rr];
        if (MODE == 0) Cf[ci] = z;
        else if (MODE == 1) Cf[ci] += z;
        else { float r = fmaxf(z, 0.f); Cb[ci] = tobf(r * r); }
      }
}

// ---------------- bf16 MFMA GEMM 64x64 (for N=768 projections) ----------------
template <int MODE>
__global__ __launch_bounds__(256) void gemm_mfma64(const __bf16* __restrict__ A, const __bf16* __restrict__ B,
                                                   float* __restrict__ Cf, __bf16* __restrict__ Cb,
                                                   int N, int K) {
  __shared__ __bf16 As[64][40];
  __shared__ __bf16 Bs[64][40];
  int bm = blockIdx.x * 64, bn = blockIdx.y * 64;
  int tid = threadIdx.x;
  int w = tid >> 6, l = tid & 63;
  int wm = (w >> 1) * 32, wn = (w & 1) * 32;
  int c = l & 15, g = l >> 4;
  int srow = tid >> 2, scol = (tid & 3) * 8;
  const __bf16* Ap = A + (size_t)(bm + srow) * K + scol;
  const __bf16* Bp = B + (size_t)(bn + srow) * K + scol;
  f32x4 acc[2][2] = {};
  for (int k0 = 0; k0 < K; k0 += 32) {
    bf16x8 av = *(const bf16x8*)(Ap + k0);
    bf16x8 bv = *(const bf16x8*)(Bp + k0);
    __syncthreads();
    *(bf16x8*)&As[srow][scol] = av;
    *(bf16x8*)&Bs[srow][scol] = bv;
    __syncthreads();
    bf16x8 af[2], bfr[2];
#pragma unroll
    for (int i = 0; i < 2; ++i) af[i] = *(const bf16x8*)&As[wm + i * 16 + c][g * 8];
#pragma unroll
    for (int j = 0; j < 2; ++j) bfr[j] = *(const bf16x8*)&Bs[wn + j * 16 + c][g * 8];
#pragma unroll
    for (int i = 0; i < 2; ++i)
#pragma unroll
      for (int j = 0; j < 2; ++j)
        acc[i][j] = __builtin_amdgcn_mfma_f32_16x16x32_bf16(af[i], bfr[j], acc[i][j], 0, 0, 0);
  }
#pragma unroll
  for (int i = 0; i < 2; ++i)
#pragma unroll
    for (int j = 0; j < 2; ++j)
#pragma unroll
      for (int rr = 0; rr < 4; ++rr) {
        int row = bm + wm + i * 16 + g * 4 + rr;
        int col = bn + wn + j * 16 + c;
        size_t ci = (size_t)row * N + col;
        float z = acc[i][j][rr];
        if (MODE == 0) Cf[ci] = z;
        else if (MODE == 1) Cf[ci] += z;
        else { float r = fmaxf(z, 0.f); Cb[ci] = tobf(r * r); }
      }
}

// ---------------- qkv post: wave per (s,h); lane l owns dims l and l+64 ----------------
__global__ __launch_bounds__(256) void qkv_post_kernel(const float* __restrict__ qkv, const float* __restrict__ vemb,
                                                       const int* __restrict__ seq, const float* __restrict__ scal,
                                                       int li, int ve_idx,
                                                       float* __restrict__ qo, float* __restrict__ ko,
                                                       float* __restrict__ vo) {
  int p = blockIdx.x * 4 + (threadIdx.x >> 6);  // p = h*NSEQ + s
  int l = threadIdx.x & 63;
  int h = p >> 11;
  int s = p & (NSEQ - 1);
  float sal0 = scal[3 * NLAY + 2 * li], sal1 = scal[3 * NLAY + 2 * li + 1];
  float fr = (l < 32) ? powf(1.0f / 1024.0f, (float)l * (1.0f / 31.0f)) : 0.f;
  float th = (float)s * fr;
  float cth = cosf(th), sth = sinf(th);
  size_t rb = (size_t)s * (3 * NHEAD * NHD) + h * NHD;
  float q0 = qkv[rb + l],                 q1 = qkv[rb + l + 64];
  float k0 = qkv[rb + NHEAD * NHD + l],   k1 = qkv[rb + NHEAD * NHD + l + 64];
  float v0 = qkv[rb + 2 * NHEAD * NHD + l], v1 = qkv[rb + 2 * NHEAD * NHD + l + 64];
  float ssq = q0 * q0 + q1 * q1;
  float ssk = k0 * k0 + k1 * k1;
#pragma unroll
  for (int o = 1; o < 64; o <<= 1) {
    ssq += __shfl_xor(ssq, o, 64);
    ssk += __shfl_xor(ssk, o, 64);
  }
  float scq = rsqrtf(ssq / (float)NHD + EPSF);
  float sck = rsqrtf(ssk / (float)NHD + EPSF);
  float qn0 = q0 * scq, qn1 = q1 * scq;
  float kn0 = k0 * sck, kn1 = k1 * sck;
  float oq0 = qn0 * cth + qn1 * sth, oq1 = -qn0 * sth + qn1 * cth;
  float ok0 = kn0 * cth + kn1 * sth, ok1 = -kn0 * sth + kn1 * cth;
  float ov0 = sal0 * v0, ov1 = sal0 * v1;
  if (ve_idx >= 0) {
    const float* ver = vemb + ((size_t)ve_idx * NVOC + seq[s]) * NDIM + h * NHD;
    ov0 += sal1 * ver[l];
    ov1 += sal1 * ver[l + 64];
  }
  size_t oo = ((size_t)h * NSEQ + s) * NHD;
  qo[oo + l] = oq0; qo[oo + l + 64] = oq1;
  ko[oo + l] = ok0; ko[oo + l + 64] = ok1;
  vo[oo + l] = ov0; vo[oo + l + 64] = ov1;
}

// ---------------- flash attention, 8 lanes per q-row, 256 threads ----------------
__global__ __launch_bounds__(256) void attn_kernel(const float* __restrict__ q, const float* __restrict__ k,
                                                   const float* __restrict__ v, const int* __restrict__ cat,
                                                   const int* __restrict__ docs, __bf16* __restrict__ y) {
  int qb = blockIdx.x;
  int h = blockIdx.y;
  int tid = threadIdx.x;
  int r = tid >> 3;
  int qt = tid & 7;
  int rg = qb * 32 + r;
  int qB = qb >> 2;
  __shared__ float Ks[32][NHD];
  __shared__ float Vs[32][NHD];
  __shared__ int kd[32];
  const float4* qp = (const float4*)(q + ((size_t)h * NSEQ + rg) * NHD + qt * 16);
  float4 qv[4];
#pragma unroll
  for (int i = 0; i < 4; ++i) qv[i] = qp[i];
  float acc[16];
#pragma unroll
  for (int i = 0; i < 16; ++i) acc[i] = 0.f;
  float mrun = -INFINITY, lrun = 0.f;
  int mydoc = docs[rg];
  int nkb = (qB + 1) * (BLKSZ / 32);
  for (int kb = 0; kb < nkb; ++kb) {
    int c = cat[qB * NBLK + (kb >> 2)];
    if (c == 0) continue;
    __syncthreads();
    {
      const float4* ksrc = (const float4*)(k + ((size_t)h * NSEQ + kb * 32) * NHD);
      const float4* vsrc = (const float4*)(v + ((size_t)h * NSEQ + kb * 32) * NHD);
      float4* kdst = (float4*)&Ks[0][0];
      float4* vdst = (float4*)&Vs[0][0];
      for (int i = tid; i < 32 * NHD / 4; i += 256) { kdst[i] = ksrc[i]; vdst[i] = vsrc[i]; }
      if (tid < 32) kd[tid] = docs[kb * 32 + tid];
    }
    __syncthreads();
    float sc[32];
#pragma unroll
    for (int kk = 0; kk < 32; ++kk) {
      const float4* kp = (const float4*)&Ks[kk][qt * 16];
      float sa = 0.f;
#pragma unroll
      for (int i = 0; i < 4; ++i) {
        float4 aa = qv[i], bb = kp[i];
        sa += aa.x * bb.x + aa.y * bb.y + aa.z * bb.z + aa.w * bb.w;
      }
      sa += __shfl_xor(sa, 1, 64);
      sa += __shfl_xor(sa, 2, 64);
      sa += __shfl_xor(sa, 4, 64);
      int kg = kb * 32 + kk;
      bool okm = (c == 2) || ((kg <= rg) && (kd[kk] == mydoc));
      sc[kk] = okm ? sa * ASCALE : -INFINITY;
    }
    float bmx = sc[0];
#pragma unroll
    for (int kk = 1; kk < 32; ++kk) bmx = fmaxf(bmx, sc[kk]);
    float mnew = fmaxf(mrun, bmx);
    if (mnew == -INFINITY) continue;
    float corr = __expf(mrun - mnew);
    lrun *= corr;
#pragma unroll
    for (int i = 0; i < 16; ++i) acc[i] *= corr;
#pragma unroll
    for (int kk = 0; kk < 32; ++kk) {
      float p = __expf(sc[kk] - mnew);
      lrun += p;
      const float* vp = &Vs[kk][qt * 16];
#pragma unroll
      for (int i = 0; i < 16; ++i) acc[i] += p * vp[i];
    }
    mrun = mnew;
  }
  float inv = 1.f / lrun;
  __bf16* yo = y + (size_t)rg * (NHEAD * NHD) + h * NHD + qt * 16;
#pragma unroll
  for (int i = 0; i < 16; ++i) yo[i] = tobf(acc[i] * inv);
}

// ---------------- MFMA logits: global_load_lds + pre-swizzled source, 2-phase pipeline ----
// LDS tile: [128 vocab rows][16 granules of 16B] per buffer, linear.
// LDS granule (row, gl) holds SOURCE granule gl ^ (row&7); read side applies same XOR.
__global__ __launch_bounds__(256) void logits_mfma_kernel(const __bf16* __restrict__ xbf,
                                                          const __bf16* __restrict__ embed_bf,
                                                          const int* __restrict__ target,
                                                          float* __restrict__ part_m, float* __restrict__ part_l,
                                                          float* __restrict__ tcap) {
  int tb = blockIdx.x;
  int ch = blockIdx.y;
  int tid = threadIdx.x;
  int w = tid >> 6;
  int l = tid & 63;
  int c = l & 15;
  int g = l >> 4;

  __shared__ __bf16 Bs[2][128 * KCH];  // 2 x 32 KB

  // A fragments: 16 token rows x full K=768 in registers.
  const __bf16* xrow = xbf + (size_t)(tb * 64 + w * 16 + c) * NDIM + g * 8;
  bf16x8 afrag[24];
#pragma unroll
  for (int kc = 0; kc < 24; ++kc) afrag[kc] = *(const bf16x8*)(xrow + kc * 32);

  int tgv[4];
#pragma unroll
  for (int rr = 0; rr < 4; ++rr) tgv[rr] = target[tb * 64 + w * 16 + g * 4 + rr];

  float rowm[4], rowl[4];
#pragma unroll
  for (int rr = 0; rr < 4; ++rr) { rowm[rr] = -INFINITY; rowl[rr] = 0.f; }

  int vbase = ch * VCHUNK;
  int rem = NVOC - vbase;
  int nvt = (rem + VTW - 1) / VTW;
  if (nvt > VCHUNK / VTW) nvt = VCHUNK / VTW;
  int totp = nvt * 6;

  // stage one phase (128 vocab rows x 128 K-elems) into Bs[p&1] via global_load_lds.
  // LDS granule L = (w*8+i)*64 + l; row = L>>4 (16 granules/row), gl = L&15;
  // source granule gs = gl ^ (row&7)  (inverse of the read-side XOR).
  auto stage = [&](int p) {
    int svt = p / 6, skc = p % 6;
    int vb0 = vbase + svt * VTW;
#pragma unroll
    for (int i = 0; i < 8; ++i) {
      int L = (w * 8 + i) * 64 + l;
      int row = L >> 4;
      int gl = L & 15;
      int gs = gl ^ (row & 7);
      int vrow = vb0 + row;
      if (vrow >= NVOC) vrow = NVOC - 1;     // clamp; masked in epilogue
      const __bf16* src = embed_bf + (size_t)vrow * NDIM + skc * KCH + gs * 8;
      __builtin_amdgcn_global_load_lds(
          (const __attribute__((address_space(1))) void*)src,
          (__attribute__((address_space(3))) void*)&Bs[p & 1][(w * 8 + i) * 512],
          16, 0, 0);
    }
  };

  stage(0);
  asm volatile("s_waitcnt vmcnt(0)" ::: "memory");
  __syncthreads();

  int p = 0;
  for (int vt = 0; vt < nvt; ++vt) {
    int vb0 = vbase + vt * VTW;
    f32x4 acc[8] = {};
    for (int kc = 0; kc < 6; ++kc, ++p) {
      if (p + 1 < totp) stage(p + 1);
      const __bf16* bb = &Bs[p & 1][0];
#pragma unroll
      for (int ks = 0; ks < 4; ++ks) {
#pragma unroll
        for (int nt = 0; nt < 8; ++nt) {
          int row = nt * 16 + c;
          int gc = (ks * 4 + g) ^ (row & 7);
          bf16x8 bfr = *(const bf16x8*)&bb[row * KCH + gc * 8];
          acc[nt] = __builtin_amdgcn_mfma_f32_16x16x32_bf16(afrag[kc * 4 + ks], bfr, acc[nt], 0, 0, 0);
        }
      }
      asm volatile("s_waitcnt vmcnt(0)" ::: "memory");
      __syncthreads();
    }
    // epilogue: soft-cap, target grab, per-row online (max, sumexp); shfl over 16 lanes
    float tmax[4];
#pragma unroll
    for (int rr = 0; rr < 4; ++rr) tmax[rr] = -INFINITY;
#pragma unroll
    for (int nt = 0; nt < 8; ++nt) {
      int vv = vb0 + nt * 16 + c;
      bool okv = vv < NVOC;
#pragma unroll
      for (int rr = 0; rr < 4; ++rr) {
        float z = acc[nt][rr];
        float cp = okv ? 15.f * z * rsqrtf(z * z + 225.f) : -INFINITY;
        tmax[rr] = fmaxf(tmax[rr], cp);
        if (okv && vv == tgv[rr]) tcap[tb * 64 + w * 16 + g * 4 + rr] = cp;
      }
    }
#pragma unroll
    for (int rr = 0; rr < 4; ++rr) {
      tmax[rr] = fmaxf(tmax[rr], __shfl_xor(tmax[rr], 1, 64));
      tmax[rr] = fmaxf(tmax[rr], __shfl_xor(tmax[rr], 2, 64));
      tmax[rr] = fmaxf(tmax[rr], __shfl_xor(tmax[rr], 4, 64));
      tmax[rr] = fmaxf(tmax[rr], __shfl_xor(tmax[rr], 8, 64));
    }
    float tsum[4] = {0.f, 0.f, 0.f, 0.f};
#pragma unroll
    for (int nt = 0; nt < 8; ++nt) {
      int vv = vb0 + nt * 16 + c;
      bool okv = vv < NVOC;
#pragma unroll
      for (int rr = 0; rr < 4; ++rr) {
        float z = acc[nt][rr];
        float cp = okv ? 15.f * z * rsqrtf(z * z + 225.f) : -INFINITY;
        tsum[rr] += __expf(cp - tmax[rr]);
      }
    }
#pragma unroll
    for (int rr = 0; rr < 4; ++rr) {
      tsum[rr] += __shfl_xor(tsum[rr], 1, 64);
      tsum[rr] += __shfl_xor(tsum[rr], 2, 64);
      tsum[rr] += __shfl_xor(tsum[rr], 4, 64);
      tsum[rr] += __shfl_xor(tsum[rr], 8, 64);
    }
#pragma unroll
    for (int rr = 0; rr < 4; ++rr) {
      float mn = fmaxf(rowm[rr], tmax[rr]);
      rowl[rr] = rowl[rr] * __expf(rowm[rr] - mn) + tsum[rr] * __expf(tmax[rr] - mn);
      rowm[rr] = mn;
    }
  }
  if (c == 0) {
#pragma unroll
    for (int rr = 0; rr < 4; ++rr) {
      int row = tb * 64 + w * 16 + g * 4 + rr;
      part_m[(size_t)ch * NSEQ + row] = rowm[rr];
      part_l[(size_t)ch * NSEQ + row] = rowl[rr];
    }
  }
}

// ---------------- final loss reduce ----------------
__global__ __launch_bounds__(256) void loss_kernel(const float* __restrict__ part_m, const float* __restrict__ part_l,
                                                   const float* __restrict__ tcap, float* __restrict__ out) {
  int tid = threadIdx.x;
  float sum = 0.f;
  for (int t = tid; t < NSEQ; t += 256) {
    float M = -INFINITY;
    for (int cc = 0; cc < NCHUNK; ++cc) M = fmaxf(M, part_m[(size_t)cc * NSEQ + t]);
    float Lq = 0.f;
    for (int cc = 0; cc < NCHUNK; ++cc) Lq += part_l[(size_t)cc * NSEQ + t] * __expf(part_m[(size_t)cc * NSEQ + t] - M);
    sum += (M + logf(Lq)) - tcap[t];
  }
  __shared__ float red[256];
  red[tid] = sum; __syncthreads();
  for (int o = 128; o > 0; o >>= 1) { if (tid < o) red[tid] += red[tid + o]; __syncthreads(); }
  if (tid == 0) out[0] = red[0] / (float)NSEQ;
}

// ---------------- host driver ----------------
extern "C" void kernel_launch(void* const* d_in, const int* in_sizes, int n_in,
                              void* d_out, int out_size, void* d_ws, size_t ws_size,
                              hipStream_t stream) {
  const int* seq   = (const int*)d_in[0];
  const int* wnb   = (const int*)d_in[1];
  const int* tgt   = (const int*)d_in[2];
  const float* embed = (const float*)d_in[3];
  const float* vemb  = (const float*)d_in[4];
  const float* qkvw  = (const float*)d_in[5];
  const float* aprj  = (const float*)d_in[6];
  const float* fcw   = (const float*)d_in[7];
  const float* prjw  = (const float*)d_in[8];
  const float* scal  = (const float*)d_in[9];
  float* out = (float*)d_out;

  char* w = (char*)d_ws;
  auto alloc = [&](size_t bytes) {
    char* p = w;
    w += (bytes + 255) & ~(size_t)255;
    return p;
  };
  int* docs = (int*)alloc(NSEQ * 4);
  int* catL = (int*)alloc(NBLK * NBLK * 4);
  int* catS = (int*)alloc(NBLK * NBLK * 4);
  float* x    = (float*)alloc((size_t)NSEQ * NDIM * 4);
  float* x0   = (float*)alloc((size_t)NSEQ * NDIM * 4);
  float* sk1  = (float*)alloc((size_t)NSEQ * NDIM * 4);
  float* sk2  = (float*)alloc((size_t)NSEQ * NDIM * 4);
  float* sk3  = (float*)alloc((size_t)NSEQ * NDIM * 4);
  float* qkvb = (float*)alloc((size_t)NSEQ * 3 * NHEAD * NHD * 4);
  float* qb   = (float*)alloc((size_t)NHEAD * NSEQ * NHD * 4);
  float* kb   = (float*)alloc((size_t)NHEAD * NSEQ * NHD * 4);
  float* vb   = (float*)alloc((size_t)NHEAD * NSEQ * NHD * 4);
  __bf16* xabf = (__bf16*)alloc((size_t)NSEQ * NDIM * 2);
  __bf16* ybf  = (__bf16*)alloc((size_t)NSEQ * NDIM * 2);
  __bf16* hbf  = (__bf16*)alloc((size_t)NSEQ * 4 * NDIM * 2);
  __bf16* xbf  = (__bf16*)alloc((size_t)NSEQ * NDIM * 2);
  float* pm   = (float*)alloc((size_t)NCHUNK * NSEQ * 4);
  float* pl   = (float*)alloc((size_t)NCHUNK * NSEQ * 4);
  float* tc   = (float*)alloc((size_t)NSEQ * 4);
  __bf16* embbf = (__bf16*)alloc((size_t)NVOC * NDIM * 2);
  __bf16* qkvwbf = (__bf16*)alloc((size_t)NLAY * 3 * NHEAD * NHD * NDIM * 2);
  __bf16* aprjbf = (__bf16*)alloc((size_t)NLAY * NDIM * NDIM * 2);
  __bf16* fcwbf  = (__bf16*)alloc((size_t)NLAY * 4 * NDIM * NDIM * 2);
  __bf16* prjwbf = (__bf16*)alloc((size_t)NLAY * NDIM * 4 * NDIM * 2);
  float* skips[4] = {nullptr, sk1, sk2, sk3};

  cvt_bf16_kernel<<<2048, 256, 0, stream>>>(embed, embbf, (long)NVOC * NDIM);
  cvt_bf16_kernel<<<2048, 256, 0, stream>>>(qkvw, qkvwbf, (long)NLAY * 3 * NHEAD * NHD * NDIM);
  cvt_bf16_kernel<<<2048, 256, 0, stream>>>(aprj, aprjbf, (long)NLAY * NDIM * NDIM);
  cvt_bf16_kernel<<<2048, 256, 0, stream>>>(fcw, fcwbf, (long)NLAY * 4 * NDIM * NDIM);
  cvt_bf16_kernel<<<2048, 256, 0, stream>>>(prjw, prjwbf, (long)NLAY * NDIM * 4 * NDIM);

  prep_kernel<<<1, 1024, 0, stream>>>(seq, wnb, docs, catL, catS);
  embed_rms_kernel<<<NSEQ, 256, 0, stream>>>(seq, embed, x, x0);

  const int velist[NLAY]   = {0, 1, 2, -1, -1, 0, 1, 2};
  const int skipj[NLAY]    = {-1, -1, -1, -1, -1, 3, 2, 1};
  const int maskLong[NLAY] = {1, 0, 0, 0, 1, 0, 0, 1};

  for (int i = 0; i < NLAY; ++i) {
    mixrms_kernel<<<NSEQ, 256, 0, stream>>>(x, x0, skipj[i] >= 0 ? skips[skipj[i]] : nullptr, scal, i, skipj[i], xabf);
    gemm_mfma<0><<<dim3(NSEQ / 128, (3 * NHEAD * NHD) / 128), 256, 0, stream>>>(
        xabf, qkvwbf + (size_t)i * 3 * NHEAD * NHD * NDIM, qkvb, nullptr, 3 * NHEAD * NHD, NDIM);
    qkv_post_kernel<<<NHEAD * NSEQ / 4, 256, 0, stream>>>(qkvb, vemb, seq, scal, i, velist[i], qb, kb, vb);
    attn_kernel<<<dim3(NSEQ / 32, NHEAD), 256, 0, stream>>>(qb, kb, vb, maskLong[i] ? catL : catS, docs, ybf);
    gemm_mfma64<1><<<dim3(NSEQ / 64, NDIM / 64), 256, 0, stream>>>(
        ybf, aprjbf + (size_t)i * NDIM * NDIM, x, nullptr, NDIM, NDIM);
    rmsbf_kernel<<<NSEQ, 256, 0, stream>>>(x, xabf);
    gemm_mfma<2><<<dim3(NSEQ / 128, (4 * NDIM) / 128), 256, 0, stream>>>(
        xabf, fcwbf + (size_t)i * 4 * NDIM * NDIM, nullptr, hbf, 4 * NDIM, NDIM);
    gemm_mfma64<1><<<dim3(NSEQ / 64, NDIM / 64), 256, 0, stream>>>(
        hbf, prjwbf + (size_t)i * NDIM * 4 * NDIM, x, nullptr, NDIM, 4 * NDIM);
    if (i >= 1 && i <= 3) {
      hipMemcpyAsync(skips[i], x, (size_t)NSEQ * NDIM * 4, hipMemcpyDeviceToDevice, stream);
    }
  }

  rmsbf_kernel<<<NSEQ, 256, 0, stream>>>(x, xbf);
  logits_mfma_kernel<<<dim3(NSEQ / 64, NCHUNK), 256, 0, stream>>>(xbf, embbf, tgt, pm, pl, tc);
  loss_kernel<<<1, 256, 0, stream>>>(pm, pl, tc, out);
}